// Round 12
// baseline (309.882 us; speedup 1.0000x reference)
//
#include <hip/hip_runtime.h>

// Problem constants: B=16, L=4096, H=8, E=64, K=64, F=2049 (rfft bins)
// Only bins m in [1,2048] matter (bin 0 excluded from top-k; out_ft uses slots 0..63).

#define NTHREADS 256

// LDS swizzle for the FFT working array: flips bits 1-3 by bits 4-6 (bijective, disjoint).
#define ZI(i) ((i) ^ ((((i) >> 4) & 7) << 1))

__device__ inline float2 f2add(float2 a, float2 b) { return make_float2(a.x + b.x, a.y + b.y); }
__device__ inline float2 f2sub(float2 a, float2 b) { return make_float2(a.x - b.x, a.y - b.y); }
// complex mul, exactly 4 VALU (mul, fma, mul, fma)
__device__ inline float2 cmulf(float2 a, float2 b) {
    return make_float2(__builtin_fmaf(a.x, b.x, -(a.y * b.y)),
                       __builtin_fmaf(a.x, b.y,  a.y * b.x));
}

// radix-8 DIT butterfly on 8 points (3 stages in registers).
__device__ inline void radix8(float2& u0, float2& u1, float2& u2, float2& u3,
                              float2& u4, float2& u5, float2& u6, float2& u7,
                              float2 wA, float2 wB, float2 wC) {
    float2 t1 = cmulf(wA, u1), t3 = cmulf(wA, u3), t5 = cmulf(wA, u5), t7 = cmulf(wA, u7);
    float2 a0 = f2add(u0, t1), a1 = f2sub(u0, t1);
    float2 a2 = f2add(u2, t3), a3 = f2sub(u2, t3);
    float2 a4 = f2add(u4, t5), a5 = f2sub(u4, t5);
    float2 a6 = f2add(u6, t7), a7 = f2sub(u6, t7);
    float2 s2 = cmulf(wB, a2), s3 = cmulf(wB, a3);
    float2 s6 = cmulf(wB, a6), s7 = cmulf(wB, a7);
    float2 b0 = f2add(a0, s2), b2 = f2sub(a0, s2);
    float2 b1 = make_float2(a1.x + s3.y, a1.y - s3.x);   // a1 + (-i)s3
    float2 b3 = make_float2(a1.x - s3.y, a1.y + s3.x);   // a1 - (-i)s3
    float2 b4 = f2add(a4, s6), b6 = f2sub(a4, s6);
    float2 b5 = make_float2(a5.x + s7.y, a5.y - s7.x);
    float2 b7 = make_float2(a5.x - s7.y, a5.y + s7.x);
    const float2 C8 = make_float2(0.70710678118654752f, -0.70710678118654752f);  // e^{-i pi/4}
    float2 wC1 = cmulf(wC, C8);
    float2 r4 = cmulf(wC, b4);
    float2 r5 = cmulf(wC1, b5);
    float2 r6t = cmulf(wC, b6);  float2 r6 = make_float2(r6t.y, -r6t.x);   // -i * wC * b6
    float2 r7t = cmulf(wC1, b7); float2 r7 = make_float2(r7t.y, -r7t.x);   // e^{-3i pi/4} wC b7
    u0 = f2add(b0, r4); u4 = f2sub(b0, r4);
    u1 = f2add(b1, r5); u5 = f2sub(b1, r5);
    u2 = f2add(b2, r6); u6 = f2sub(b2, r6);
    u3 = f2add(b3, r7); u7 = f2sub(b3, r7);
}

// ---------------- table kernel: trig[k] = (cos, sin)(2*pi*k/4096), f64-accurate ----------------
__global__ void k_tables(float2* __restrict__ trig) {
    int k = blockIdx.x * blockDim.x + threadIdx.x;
    if (k < 4096) {
        double th = (6.283185307179586476925286766559 * (double)k) / 4096.0;
        trig[k] = make_float2((float)cos(th), (float)sin(th));
    }
}

// ---------------- transpose + bit-reversal: q[b,l,h,e] -> T[(b,h,eo)][p][j] (float2) -----------
// 128-row tiles (33 KB LDS -> 4 blocks/CU). Block (b:16, h:8, c5:32).
__global__ __launch_bounds__(256) void k_xpose(const float* __restrict__ q,
                                               float2* __restrict__ T) {
    __shared__ float tile[128][65];  // 33 KB, padded (+1)

    const int tid = threadIdx.x;
    const int bi  = blockIdx.x;
    const int b   = bi >> 8;
    const int h   = (bi >> 5) & 7;
    const int c5  = bi & 31;

    const float* qb = q + ((size_t)b * 4096 * 512) + (size_t)h * 64;
#pragma unroll
    for (int i = 0; i < 8; ++i) {
        const int f = tid + 256 * i;
        const int t = f >> 4, e4 = f & 15;
        const float4 v = *(const float4*)(qb + (size_t)(c5 + 32 * t) * 512 + e4 * 4);
        tile[t][e4 * 4 + 0] = v.x;
        tile[t][e4 * 4 + 1] = v.y;
        tile[t][e4 * 4 + 2] = v.z;
        tile[t][e4 * 4 + 3] = v.w;
    }
    __syncthreads();

    const int wave = tid >> 6, lane = tid & 63;
    const int rl  = __brev(lane) >> 26;  // rev6(lane)
    const int r5c = __brev(c5) >> 27;    // rev5(c5)
    for (int cc = wave; cc < 32; cc += 4) {
        const int eo = cc >> 2, p = cc & 3;
        const int col0 = eo * 8 + 2 * p;
        float2* dst = T + ((size_t)((b * 8 + h) * 8 + eo)) * 16384 + (size_t)p * 4096
                        + (size_t)r5c * 128;
        float4 o;
        o.x = tile[rl][col0];      o.y = tile[rl][col0 + 1];
        o.z = tile[rl + 64][col0]; o.w = tile[rl + 64][col0 + 1];
        *(float4*)(dst + 2 * lane) = o;  // 16B/lane, contiguous 1KB run per (eo,p)
    }
}

// ---------------- FFT: ONE plane per block (4096 blocks) ---------------------------------------
// Each block: load its 32KB plane, 4 radix-8 passes in LDS, unpack + store spectrum in place,
// per-thread 8-bin energy accumulation -> one u64 atomic per bin per block. Plane-per-block
// removes the serial 4-plane barrier chain (24 -> 6 barriers) and quadruples schedulable blocks.
__global__ __launch_bounds__(256) void k_fft(const float2* __restrict__ trig,
                                             float2* __restrict__ Xout,
                                             unsigned long long* __restrict__ score) {
    __shared__ float2 z[4096];     // 32 KB (swizzled indexing)
    __shared__ float2 ctw[1752];   // 13.7 KB: [0,24) pass1, [24,216) pass2, [216,1752) pass3

    const int tid = threadIdx.x;
    const int gbi = blockIdx.x >> 2;   // signal-octet id
    const int p   = blockIdx.x & 3;    // plane within octet

    // build compact twiddle triples: ctw[off + 3j + {0,1,2}] = conj(trig[j << {sA, sA-1, sA-2}])
    for (int t = tid; t < 584; t += NTHREADS) {
        int off, j, sA;
        if (t < 8)       { off = 0;   j = t;      sA = 8; }   // pass1 (st=4,  h=8,   j<8)
        else if (t < 72) { off = 24;  j = t - 8;  sA = 5; }   // pass2 (st=7,  h=64,  j<64)
        else             { off = 216; j = t - 72; sA = 2; }   // pass3 (st=10, h=512, j<512)
        float2 a = trig[j << sA], b = trig[j << (sA - 1)], c = trig[j << (sA - 2)];
        ctw[off + 3 * j + 0] = make_float2(a.x, -a.y);
        ctw[off + 3 * j + 1] = make_float2(b.x, -b.y);
        ctw[off + 3 * j + 2] = make_float2(c.x, -c.y);
    }

    const float2 ONE = make_float2(1.0f, 0.0f);
    const float2* plane = Xout + (size_t)gbi * 16384 + (size_t)p * 4096;

    // pass 0 (stages 1-3, unit twiddles): load 8 contiguous points, radix-8, store swizzled
#pragma unroll
    for (int it = 0; it < 2; ++it) {
        const int t = tid + 256 * it;
        const float4 v01 = *(const float4*)(plane + 8 * t);
        const float4 v23 = *(const float4*)(plane + 8 * t + 2);
        const float4 v45 = *(const float4*)(plane + 8 * t + 4);
        const float4 v67 = *(const float4*)(plane + 8 * t + 6);
        float2 u0 = make_float2(v01.x, v01.y), u1 = make_float2(v01.z, v01.w);
        float2 u2 = make_float2(v23.x, v23.y), u3 = make_float2(v23.z, v23.w);
        float2 u4 = make_float2(v45.x, v45.y), u5 = make_float2(v45.z, v45.w);
        float2 u6 = make_float2(v67.x, v67.y), u7 = make_float2(v67.z, v67.w);
        radix8(u0, u1, u2, u3, u4, u5, u6, u7, ONE, ONE, ONE);
        const int i0 = 8 * t;
        z[ZI(i0 + 0)] = u0; z[ZI(i0 + 1)] = u1; z[ZI(i0 + 2)] = u2; z[ZI(i0 + 3)] = u3;
        z[ZI(i0 + 4)] = u4; z[ZI(i0 + 5)] = u5; z[ZI(i0 + 6)] = u6; z[ZI(i0 + 7)] = u7;
    }
    __syncthreads();  // z + ctw ready

    // passes 1..3: stages (4,5,6), (7,8,9), (10,11,12); h = 8, 64, 512
#pragma unroll
    for (int p8 = 1; p8 <= 3; ++p8) {
        const int st  = 1 + 3 * p8;
        const int h   = 1 << (st - 1);
        const int off = (p8 == 1) ? 0 : (p8 == 2) ? 24 : 216;
        for (int t = tid; t < 512; t += NTHREADS) {
            const int j = t & (h - 1);
            const int g = t >> (st - 1);
            const int i0 = (g << (st + 2)) + j;
            int a0 = ZI(i0),         a1 = ZI(i0 + h),     a2 = ZI(i0 + 2 * h), a3 = ZI(i0 + 3 * h);
            int a4 = ZI(i0 + 4 * h), a5 = ZI(i0 + 5 * h), a6 = ZI(i0 + 6 * h), a7 = ZI(i0 + 7 * h);
            float2 u0 = z[a0], u1 = z[a1], u2 = z[a2], u3 = z[a3];
            float2 u4 = z[a4], u5 = z[a5], u6 = z[a6], u7 = z[a7];
            const float2 wA = ctw[off + 3 * j + 0];
            const float2 wB = ctw[off + 3 * j + 1];
            const float2 wC = ctw[off + 3 * j + 2];
            radix8(u0, u1, u2, u3, u4, u5, u6, u7, wA, wB, wC);
            z[a0] = u0; z[a1] = u1; z[a2] = u2; z[a3] = u3;
            z[a4] = u4; z[a5] = u5; z[a6] = u6; z[a7] = u7;
        }
        __syncthreads();
    }

    // unpack two real spectra; store (overwrites this block's own plane); energy -> atomics
    {
        const size_t s0 = (size_t)gbi * 16384 + (size_t)p * 4096;  // = signal (gbi*8+2p) * 2048
#pragma unroll
        for (int k = 0; k < 8; ++k) {
            const int t = tid + 256 * k;
            const int m = t + 1;
            float2 Za = z[ZI(m)];
            float2 Zb = z[ZI(4096 - m)];
            float Xr0 = 0.5f * (Za.x + Zb.x);
            float Xi0 = 0.5f * (Za.y - Zb.y);
            float Xr1 = 0.5f * (Za.y + Zb.y);
            float Xi1 = 0.5f * (Zb.x - Za.x);
            Xout[s0 + t]        = make_float2(Xr0, Xi0);
            Xout[s0 + 2048 + t] = make_float2(Xr1, Xi1);
            float e = Xr0 * Xr0 + Xi0 * Xi0 + Xr1 * Xr1 + Xi1 * Xi1;
            unsigned long long v = (unsigned long long)llrintf(e * 1048576.0f);  // 2^20
            atomicAdd(&score[t], v);
        }
    }
}

// ---------------- top-64, parallelized: 8 blocks x 256 threads, one candidate per thread -------
__global__ __launch_bounds__(256) void k_topk(const unsigned long long* __restrict__ score,
                                              int* __restrict__ idx) {
    __shared__ unsigned long long s[2048];
    const int tid = threadIdx.x;
    for (int t = tid; t < 2048; t += 256) s[t] = score[t];
    __syncthreads();

    const int t = blockIdx.x * 256 + tid;  // 0..2047
    const unsigned long long my = s[t];
    int rank = 0;
#pragma unroll 8
    for (int u = 0; u < 2048; ++u) {
        unsigned long long o = s[u];
        rank += (int)((o > my) || (o == my && u < t));
    }
    if (rank < 64) idx[rank] = t + 1;  // store frequency index m
}

// ---------------- gather + complex projection: Y[b,j,h,f] = sum_e X[b,idx_j,h,e] * W[j,h,e,f] ----
__global__ __launch_bounds__(256) void k_proj(const float2* __restrict__ X,
                                              const float* __restrict__ wr,
                                              const float* __restrict__ wi,
                                              const int* __restrict__ idx,
                                              float2* __restrict__ Y) {
    __shared__ float2 xs[16 * 64];   // [b][e]  8 KB
    __shared__ float  wrs[64 * 64];  // [e][f] 16 KB
    __shared__ float  wis[64 * 64];  // 16 KB

    const int tid = threadIdx.x;
    const int j = blockIdx.x >> 3;
    const int h = blockIdx.x & 7;
    const int m = idx[j];

    for (int t = tid; t < 1024; t += NTHREADS) {
        int b = t >> 6, e = t & 63;
        xs[t] = X[((size_t)((b * 8 + h) * 64 + e)) * 2048 + (size_t)(m - 1)];
    }
    const float* wrb = wr + ((size_t)(j * 8 + h)) * 4096;
    const float* wib = wi + ((size_t)(j * 8 + h)) * 4096;
    for (int t = tid; t < 4096; t += NTHREADS) { wrs[t] = wrb[t]; wis[t] = wib[t]; }
    __syncthreads();

    const int b  = tid >> 4;   // 0..15
    const int fg = tid & 15;   // 0..15
    for (int fo = 0; fo < 4; ++fo) {
        int f = fg * 4 + fo;
        float yr = 0.f, yi = 0.f;
        for (int e = 0; e < 64; ++e) {
            float2 x = xs[b * 64 + e];
            float a = wrs[e * 64 + f], c = wis[e * 64 + f];
            yr = __builtin_fmaf(x.x, a, yr); yr = __builtin_fmaf(-x.y, c, yr);
            yi = __builtin_fmaf(x.x, c, yi); yi = __builtin_fmaf( x.y, a, yi);
        }
        Y[((size_t)b * 64 + j) * 512 + (size_t)(h * 64 + f)] = make_float2(yr, yi);
    }
}

// ---------------- synthesis with full w-symmetry: 1 rotator -> 4 output rows -------------------
//   out(l)      = F0+F1+F2+F3          out(l+2048) = F0-F1+F2-F3
//   out(l+1024) = (F0-F2)-(H1-H3)      out(l+3072) = (F0-F2)+(H1-H3)
__global__ __launch_bounds__(256, 2) void k_synth(const float2* __restrict__ Y,
                                                  const float2* __restrict__ trig,
                                                  float* __restrict__ out) {
    __shared__ __align__(16) float2 ys[64][64];  // 32 KB, pre-scaled

    const int tid = threadIdx.x;
    const int bi  = blockIdx.x;
    const int b   = bi >> 7;        // 16
    const int hft = (bi >> 4) & 7;  // 8
    const int lt  = bi & 15;        // 16

    const float invN = 1.0f / 4096.0f;
    const float2* yb = Y + (size_t)b * 64 * 512 + (size_t)hft * 64;
    for (int t = tid; t < 64 * 64; t += NTHREADS) {
        int j = t >> 6, cc = t & 63;
        float2 y = yb[(size_t)j * 512 + cc];
        if (j == 0) ys[0][cc] = make_float2(y.x * invN, 0.0f);
        else        ys[j][cc] = make_float2(y.x * (2.0f * invN), y.y * (2.0f * invN));
    }
    __syncthreads();

    const int r = tid >> 3;          // 0..31
    const int c = tid & 7;           // 0..7
    const int l0 = lt * 64 + r * 2;  // base l (v=0) in [0, 1024)

    float2 rot[2], w[2];
#pragma unroll
    for (int v = 0; v < 2; ++v) {
        w[v] = trig[(l0 + v) & 4095];
        rot[v] = make_float2(1.0f, 0.0f);
    }

    float F0[2][8], F1[2][8], F2[2][8], F3[2][8], H1[2][8], H3[2][8];
#pragma unroll
    for (int v = 0; v < 2; ++v)
#pragma unroll
        for (int u = 0; u < 8; ++u) {
            F0[v][u] = F1[v][u] = F2[v][u] = F3[v][u] = 0.0f;
            H1[v][u] = H3[v][u] = 0.0f;
        }

    // b128 LDS loads: yv[2k], yv[2k+1] are consecutive float2s at ys[j][c*2 + 16k]
#define LOAD_YV(JROW)                                                        \
    float2 yv[8];                                                            \
    _Pragma("unroll")                                                        \
    for (int k4 = 0; k4 < 4; ++k4) {                                         \
        const float4 t4 = *(const float4*)&ys[(JROW)][c * 2 + k4 * 16];      \
        yv[2 * k4]     = make_float2(t4.x, t4.y);                            \
        yv[2 * k4 + 1] = make_float2(t4.z, t4.w);                            \
    }

    for (int j = 0; j < 64; j += 4) {
        // j+0 (even) -> F0
        {
            LOAD_YV(j)
#pragma unroll
            for (int v = 0; v < 2; ++v) {
                const float cx = rot[v].x, sx = rot[v].y;
#pragma unroll
                for (int u = 0; u < 8; ++u) {
                    float a = F0[v][u];
                    a = __builtin_fmaf(cx, yv[u].x, a);
                    a = __builtin_fmaf(-sx, yv[u].y, a);
                    F0[v][u] = a;
                }
                float nx = __builtin_fmaf(rot[v].x, w[v].x, -(rot[v].y * w[v].y));
                float ny = __builtin_fmaf(rot[v].x, w[v].y,  (rot[v].y * w[v].x));
                rot[v] = make_float2(nx, ny);
            }
        }
        // j+1 (odd) -> F1, H1
        {
            LOAD_YV(j + 1)
#pragma unroll
            for (int v = 0; v < 2; ++v) {
                const float cx = rot[v].x, sx = rot[v].y;
#pragma unroll
                for (int u = 0; u < 8; ++u) {
                    float a = F1[v][u], g = H1[v][u];
                    a = __builtin_fmaf(cx, yv[u].x, a);
                    a = __builtin_fmaf(-sx, yv[u].y, a);
                    g = __builtin_fmaf(sx, yv[u].x, g);
                    g = __builtin_fmaf(cx, yv[u].y, g);
                    F1[v][u] = a; H1[v][u] = g;
                }
                float nx = __builtin_fmaf(rot[v].x, w[v].x, -(rot[v].y * w[v].y));
                float ny = __builtin_fmaf(rot[v].x, w[v].y,  (rot[v].y * w[v].x));
                rot[v] = make_float2(nx, ny);
            }
        }
        // j+2 (even) -> F2
        {
            LOAD_YV(j + 2)
#pragma unroll
            for (int v = 0; v < 2; ++v) {
                const float cx = rot[v].x, sx = rot[v].y;
#pragma unroll
                for (int u = 0; u < 8; ++u) {
                    float a = F2[v][u];
                    a = __builtin_fmaf(cx, yv[u].x, a);
                    a = __builtin_fmaf(-sx, yv[u].y, a);
                    F2[v][u] = a;
                }
                float nx = __builtin_fmaf(rot[v].x, w[v].x, -(rot[v].y * w[v].y));
                float ny = __builtin_fmaf(rot[v].x, w[v].y,  (rot[v].y * w[v].x));
                rot[v] = make_float2(nx, ny);
            }
        }
        // j+3 (odd) -> F3, H3
        {
            LOAD_YV(j + 3)
#pragma unroll
            for (int v = 0; v < 2; ++v) {
                const float cx = rot[v].x, sx = rot[v].y;
#pragma unroll
                for (int u = 0; u < 8; ++u) {
                    float a = F3[v][u], g = H3[v][u];
                    a = __builtin_fmaf(cx, yv[u].x, a);
                    a = __builtin_fmaf(-sx, yv[u].y, a);
                    g = __builtin_fmaf(sx, yv[u].x, g);
                    g = __builtin_fmaf(cx, yv[u].y, g);
                    F3[v][u] = a; H3[v][u] = g;
                }
                float nx = __builtin_fmaf(rot[v].x, w[v].x, -(rot[v].y * w[v].y));
                float ny = __builtin_fmaf(rot[v].x, w[v].y,  (rot[v].y * w[v].x));
                rot[v] = make_float2(nx, ny);
            }
        }
    }
#undef LOAD_YV

    // stores: 4 rows per (v): l0+v, +1024, +2048, +3072
#pragma unroll
    for (int v = 0; v < 2; ++v) {
        float* o0 = out + ((size_t)(b * 4096 + l0 + v)) * 512 + (size_t)hft * 64;
        float* o1 = o0 + (size_t)1024 * 512;
        float* o2 = o0 + (size_t)2048 * 512;
        float* o3 = o0 + (size_t)3072 * 512;
#pragma unroll
        for (int k = 0; k < 4; ++k) {
            float2 s0, s1, s2, s3;
#pragma unroll
            for (int d = 0; d < 2; ++d) {
                const int u = 2 * k + d;
                const float p = F0[v][u] + F2[v][u];
                const float m = F0[v][u] - F2[v][u];
                const float q = F1[v][u] + F3[v][u];
                const float hh = H3[v][u] - H1[v][u];
                ((float*)&s0)[d] = p + q;
                ((float*)&s2)[d] = p - q;
                ((float*)&s1)[d] = m + hh;
                ((float*)&s3)[d] = m - hh;
            }
            *(float2*)(o0 + k * 16 + c * 2) = s0;
            *(float2*)(o1 + k * 16 + c * 2) = s1;
            *(float2*)(o2 + k * 16 + c * 2) = s2;
            *(float2*)(o3 + k * 16 + c * 2) = s3;
        }
    }
}

// ---------------- launch ----------------
extern "C" void kernel_launch(void* const* d_in, const int* in_sizes, int n_in,
                              void* d_out, int out_size, void* d_ws, size_t ws_size,
                              hipStream_t stream) {
    const float* q  = (const float*)d_in[0];
    const float* wr = (const float*)d_in[3];
    const float* wi = (const float*)d_in[4];

    char* ws = (char*)d_ws;
    float2*             trig  = (float2*)(ws + 0);                  // 32 KB
    unsigned long long* score = (unsigned long long*)(ws + 32768);  // 16 KB
    int*                idx   = (int*)(ws + 49152);                 // 256 B
    float2*             Y     = (float2*)(ws + 65536);              // 4 MB

    // d_out triples as: transposed-q scratch T -> spectrum Xout (in-place) -> final output.
    float2* Xs = (float2*)d_out;

    hipMemsetAsync(score, 0, 2048 * sizeof(unsigned long long), stream);
    k_tables<<<16, 256, 0, stream>>>(trig);
    k_xpose<<<4096, 256, 0, stream>>>(q, Xs);          // (b:16, h:8, c5:32), 128-row tiles
    k_fft<<<4096, 256, 0, stream>>>(trig, Xs, score);  // ONE plane per block, in place
    k_topk<<<8, 256, 0, stream>>>(score, idx);         // 2048 candidates, 1/thread
    k_proj<<<512, 256, 0, stream>>>(Xs, wr, wi, idx, Y);
    k_synth<<<2048, 256, 0, stream>>>(Y, trig, (float*)d_out);  // (b:16, hft:8, lt:16)
}

// Round 13
// 253.467 us; speedup vs baseline: 1.2226x; 1.2226x over previous
//
#include <hip/hip_runtime.h>

// Problem constants: B=16, L=4096, H=8, E=64, K=64, F=2049 (rfft bins)
// Only bins m in [1,2048] matter (bin 0 excluded from top-k; out_ft uses slots 0..63).

#define NTHREADS 256

// LDS swizzle for the FFT working array: flips bits 1-3 by bits 4-6 (bijective, disjoint).
#define ZI(i) ((i) ^ ((((i) >> 4) & 7) << 1))

__device__ inline float2 f2add(float2 a, float2 b) { return make_float2(a.x + b.x, a.y + b.y); }
__device__ inline float2 f2sub(float2 a, float2 b) { return make_float2(a.x - b.x, a.y - b.y); }
// complex mul, exactly 4 VALU (mul, fma, mul, fma)
__device__ inline float2 cmulf(float2 a, float2 b) {
    return make_float2(__builtin_fmaf(a.x, b.x, -(a.y * b.y)),
                       __builtin_fmaf(a.x, b.y,  a.y * b.x));
}

// radix-8 DIT butterfly on 8 points (3 stages in registers).
__device__ inline void radix8(float2& u0, float2& u1, float2& u2, float2& u3,
                              float2& u4, float2& u5, float2& u6, float2& u7,
                              float2 wA, float2 wB, float2 wC) {
    float2 t1 = cmulf(wA, u1), t3 = cmulf(wA, u3), t5 = cmulf(wA, u5), t7 = cmulf(wA, u7);
    float2 a0 = f2add(u0, t1), a1 = f2sub(u0, t1);
    float2 a2 = f2add(u2, t3), a3 = f2sub(u2, t3);
    float2 a4 = f2add(u4, t5), a5 = f2sub(u4, t5);
    float2 a6 = f2add(u6, t7), a7 = f2sub(u6, t7);
    float2 s2 = cmulf(wB, a2), s3 = cmulf(wB, a3);
    float2 s6 = cmulf(wB, a6), s7 = cmulf(wB, a7);
    float2 b0 = f2add(a0, s2), b2 = f2sub(a0, s2);
    float2 b1 = make_float2(a1.x + s3.y, a1.y - s3.x);   // a1 + (-i)s3
    float2 b3 = make_float2(a1.x - s3.y, a1.y + s3.x);   // a1 - (-i)s3
    float2 b4 = f2add(a4, s6), b6 = f2sub(a4, s6);
    float2 b5 = make_float2(a5.x + s7.y, a5.y - s7.x);
    float2 b7 = make_float2(a5.x - s7.y, a5.y + s7.x);
    const float2 C8 = make_float2(0.70710678118654752f, -0.70710678118654752f);  // e^{-i pi/4}
    float2 wC1 = cmulf(wC, C8);
    float2 r4 = cmulf(wC, b4);
    float2 r5 = cmulf(wC1, b5);
    float2 r6t = cmulf(wC, b6);  float2 r6 = make_float2(r6t.y, -r6t.x);   // -i * wC * b6
    float2 r7t = cmulf(wC1, b7); float2 r7 = make_float2(r7t.y, -r7t.x);   // e^{-3i pi/4} wC b7
    u0 = f2add(b0, r4); u4 = f2sub(b0, r4);
    u1 = f2add(b1, r5); u5 = f2sub(b1, r5);
    u2 = f2add(b2, r6); u6 = f2sub(b2, r6);
    u3 = f2add(b3, r7); u7 = f2sub(b3, r7);
}

// ---------------- table kernel: trig[k] = (cos, sin)(2*pi*k/4096), f64-accurate ----------------
__global__ void k_tables(float2* __restrict__ trig) {
    int k = blockIdx.x * blockDim.x + threadIdx.x;
    if (k < 4096) {
        double th = (6.283185307179586476925286766559 * (double)k) / 4096.0;
        trig[k] = make_float2((float)cos(th), (float)sin(th));
    }
}

// ---------------- transpose + bit-reversal: q[b,l,h,e] -> T[(b,h,eo)][p][j] (float2) -----------
// 128-row tiles (33 KB LDS -> 4 blocks/CU). Block (b:16, h:8, c5:32).
__global__ __launch_bounds__(256) void k_xpose(const float* __restrict__ q,
                                               float2* __restrict__ T) {
    __shared__ float tile[128][65];  // 33 KB, padded (+1)

    const int tid = threadIdx.x;
    const int bi  = blockIdx.x;
    const int b   = bi >> 8;
    const int h   = (bi >> 5) & 7;
    const int c5  = bi & 31;

    const float* qb = q + ((size_t)b * 4096 * 512) + (size_t)h * 64;
#pragma unroll
    for (int i = 0; i < 8; ++i) {
        const int f = tid + 256 * i;
        const int t = f >> 4, e4 = f & 15;
        const float4 v = *(const float4*)(qb + (size_t)(c5 + 32 * t) * 512 + e4 * 4);
        tile[t][e4 * 4 + 0] = v.x;
        tile[t][e4 * 4 + 1] = v.y;
        tile[t][e4 * 4 + 2] = v.z;
        tile[t][e4 * 4 + 3] = v.w;
    }
    __syncthreads();

    const int wave = tid >> 6, lane = tid & 63;
    const int rl  = __brev(lane) >> 26;  // rev6(lane)
    const int r5c = __brev(c5) >> 27;    // rev5(c5)
    for (int cc = wave; cc < 32; cc += 4) {
        const int eo = cc >> 2, p = cc & 3;
        const int col0 = eo * 8 + 2 * p;
        float2* dst = T + ((size_t)((b * 8 + h) * 8 + eo)) * 16384 + (size_t)p * 4096
                        + (size_t)r5c * 128;
        float4 o;
        o.x = tile[rl][col0];      o.y = tile[rl][col0 + 1];
        o.z = tile[rl + 64][col0]; o.w = tile[rl + 64][col0 + 1];
        *(float4*)(dst + 2 * lane) = o;  // 16B/lane, contiguous 1KB run per (eo,p)
    }
}

// ---------------- FFT (4 x radix-8 passes) + spectrum store + score accumulation ----------------
// R11 structure (1024 blocks, 4-plane register-prefetch pipeline, eacc in registers).
// Occupancy lever: pass-3 twiddles read directly from global trig (L1-resident 32KB table,
// near-consecutive addresses) instead of a 12KB LDS table -> LDS 33.7KB -> 4 blocks/CU.
__global__ __launch_bounds__(256) void k_fft(const float2* __restrict__ trig,
                                             float2* __restrict__ Xout,
                                             unsigned long long* __restrict__ score) {
    __shared__ float2 z[4096];     // 32 KB (swizzled indexing)
    __shared__ float2 ctw[216];    // 1.7 KB: [0,24) pass1 triples, [24,216) pass2 triples

    const int tid = threadIdx.x;
    const int bi  = blockIdx.x;

    // build compact twiddle triples for passes 1-2 only
    if (tid < 72) {
        int off, j, sA;
        if (tid < 8) { off = 0;  j = tid;     sA = 8; }   // pass1 (st=4, h=8,  j<8)
        else         { off = 24; j = tid - 8; sA = 5; }   // pass2 (st=7, h=64, j<64)
        float2 a = trig[j << sA], b = trig[j << (sA - 1)], c = trig[j << (sA - 2)];
        ctw[off + 3 * j + 0] = make_float2(a.x, -a.y);
        ctw[off + 3 * j + 1] = make_float2(b.x, -b.y);
        ctw[off + 3 * j + 2] = make_float2(c.x, -c.y);
    }

    float eaccr[8];
#pragma unroll
    for (int k = 0; k < 8; ++k) eaccr[k] = 0.f;

    const float2 ONE = make_float2(1.0f, 0.0f);
    const float2* base = Xout + (size_t)bi * 16384;

    // prefetch plane 0 into registers (2 items/thread x 4 float4)
    float4 pre[2][4];
#pragma unroll
    for (int it = 0; it < 2; ++it) {
        const int t = tid + 256 * it;
#pragma unroll
        for (int g = 0; g < 4; ++g) pre[it][g] = *(const float4*)(base + 8 * t + 2 * g);
    }
    __syncthreads();  // ctw ready

    for (int p = 0; p < 4; ++p) {
        // move prefetched data to cur, then immediately issue next plane's loads
        float4 cur[2][4];
#pragma unroll
        for (int it = 0; it < 2; ++it)
#pragma unroll
            for (int g = 0; g < 4; ++g) cur[it][g] = pre[it][g];

        if (p < 3) {
            const float2* pn = base + (size_t)(p + 1) * 4096;
#pragma unroll
            for (int it = 0; it < 2; ++it) {
                const int t = tid + 256 * it;
#pragma unroll
                for (int g = 0; g < 4; ++g) pre[it][g] = *(const float4*)(pn + 8 * t + 2 * g);
            }
        }

        // pass 0 (stages 1-3, unit twiddles) on registers; store swizzled to LDS
#pragma unroll
        for (int it = 0; it < 2; ++it) {
            const int t = tid + 256 * it;
            float2 u0 = make_float2(cur[it][0].x, cur[it][0].y);
            float2 u1 = make_float2(cur[it][0].z, cur[it][0].w);
            float2 u2 = make_float2(cur[it][1].x, cur[it][1].y);
            float2 u3 = make_float2(cur[it][1].z, cur[it][1].w);
            float2 u4 = make_float2(cur[it][2].x, cur[it][2].y);
            float2 u5 = make_float2(cur[it][2].z, cur[it][2].w);
            float2 u6 = make_float2(cur[it][3].x, cur[it][3].y);
            float2 u7 = make_float2(cur[it][3].z, cur[it][3].w);
            radix8(u0, u1, u2, u3, u4, u5, u6, u7, ONE, ONE, ONE);
            const int i0 = 8 * t;
            z[ZI(i0 + 0)] = u0; z[ZI(i0 + 1)] = u1; z[ZI(i0 + 2)] = u2; z[ZI(i0 + 3)] = u3;
            z[ZI(i0 + 4)] = u4; z[ZI(i0 + 5)] = u5; z[ZI(i0 + 6)] = u6; z[ZI(i0 + 7)] = u7;
        }
        __syncthreads();

        // passes 1..3: stages (4,5,6), (7,8,9), (10,11,12); h = 8, 64, 512
#pragma unroll
        for (int p8 = 1; p8 <= 3; ++p8) {
            const int st  = 1 + 3 * p8;
            const int h   = 1 << (st - 1);
            for (int t = tid; t < 512; t += NTHREADS) {
                const int j = t & (h - 1);
                const int g = t >> (st - 1);
                const int i0 = (g << (st + 2)) + j;
                int a0 = ZI(i0),         a1 = ZI(i0 + h),     a2 = ZI(i0 + 2 * h), a3 = ZI(i0 + 3 * h);
                int a4 = ZI(i0 + 4 * h), a5 = ZI(i0 + 5 * h), a6 = ZI(i0 + 6 * h), a7 = ZI(i0 + 7 * h);
                float2 u0 = z[a0], u1 = z[a1], u2 = z[a2], u3 = z[a3];
                float2 u4 = z[a4], u5 = z[a5], u6 = z[a6], u7 = z[a7];
                float2 wA, wB, wC;
                if (p8 < 3) {
                    const int off = (p8 == 1) ? 0 : 24;
                    wA = ctw[off + 3 * j + 0];
                    wB = ctw[off + 3 * j + 1];
                    wC = ctw[off + 3 * j + 2];
                } else {
                    // pass3: read from global trig (L1-resident), conj inline
                    float2 a = trig[j << 2], b = trig[j << 1], c = trig[j];
                    wA = make_float2(a.x, -a.y);
                    wB = make_float2(b.x, -b.y);
                    wC = make_float2(c.x, -c.y);
                }
                radix8(u0, u1, u2, u3, u4, u5, u6, u7, wA, wB, wC);
                z[a0] = u0; z[a1] = u1; z[a2] = u2; z[a3] = u3;
                z[a4] = u4; z[a5] = u5; z[a6] = u6; z[a7] = u7;
            }
            __syncthreads();
        }

        // unpack two real spectra; store (overwrites this pair's own plane); accumulate energy
        {
            const size_t s0 = (size_t)bi * 16384 + (size_t)p * 4096;  // = signal (bi*8+2p) * 2048
#pragma unroll
            for (int k = 0; k < 8; ++k) {
                const int t = tid + 256 * k;
                const int m = t + 1;
                float2 Za = z[ZI(m)];
                float2 Zb = z[ZI(4096 - m)];
                float Xr0 = 0.5f * (Za.x + Zb.x);
                float Xi0 = 0.5f * (Za.y - Zb.y);
                float Xr1 = 0.5f * (Za.y + Zb.y);
                float Xi1 = 0.5f * (Zb.x - Za.x);
                Xout[s0 + t]        = make_float2(Xr0, Xi0);
                Xout[s0 + 2048 + t] = make_float2(Xr1, Xi1);
                eaccr[k] += Xr0 * Xr0 + Xi0 * Xi0 + Xr1 * Xr1 + Xi1 * Xi1;
            }
        }
        __syncthreads();  // protect z before next plane's pass-0 stores
    }

    // deterministic reduction: fixed-point u64 atomics (integer adds commute exactly)
#pragma unroll
    for (int k = 0; k < 8; ++k) {
        unsigned long long v = (unsigned long long)llrintf(eaccr[k] * 1048576.0f);  // 2^20
        atomicAdd(&score[tid + 256 * k], v);
    }
}

// ---------------- top-64, parallelized: 8 blocks x 256 threads, one candidate per thread -------
__global__ __launch_bounds__(256) void k_topk(const unsigned long long* __restrict__ score,
                                              int* __restrict__ idx) {
    __shared__ unsigned long long s[2048];
    const int tid = threadIdx.x;
    for (int t = tid; t < 2048; t += 256) s[t] = score[t];
    __syncthreads();

    const int t = blockIdx.x * 256 + tid;  // 0..2047
    const unsigned long long my = s[t];
    int rank = 0;
#pragma unroll 8
    for (int u = 0; u < 2048; ++u) {
        unsigned long long o = s[u];
        rank += (int)((o > my) || (o == my && u < t));
    }
    if (rank < 64) idx[rank] = t + 1;  // store frequency index m
}

// ---------------- gather + complex projection: Y[b,j,h,f] = sum_e X[b,idx_j,h,e] * W[j,h,e,f] ----
__global__ __launch_bounds__(256) void k_proj(const float2* __restrict__ X,
                                              const float* __restrict__ wr,
                                              const float* __restrict__ wi,
                                              const int* __restrict__ idx,
                                              float2* __restrict__ Y) {
    __shared__ float2 xs[16 * 64];   // [b][e]  8 KB
    __shared__ float  wrs[64 * 64];  // [e][f] 16 KB
    __shared__ float  wis[64 * 64];  // 16 KB

    const int tid = threadIdx.x;
    const int j = blockIdx.x >> 3;
    const int h = blockIdx.x & 7;
    const int m = idx[j];

    for (int t = tid; t < 1024; t += NTHREADS) {
        int b = t >> 6, e = t & 63;
        xs[t] = X[((size_t)((b * 8 + h) * 64 + e)) * 2048 + (size_t)(m - 1)];
    }
    const float* wrb = wr + ((size_t)(j * 8 + h)) * 4096;
    const float* wib = wi + ((size_t)(j * 8 + h)) * 4096;
    for (int t = tid; t < 4096; t += NTHREADS) { wrs[t] = wrb[t]; wis[t] = wib[t]; }
    __syncthreads();

    const int b  = tid >> 4;   // 0..15
    const int fg = tid & 15;   // 0..15
    for (int fo = 0; fo < 4; ++fo) {
        int f = fg * 4 + fo;
        float yr = 0.f, yi = 0.f;
        for (int e = 0; e < 64; ++e) {
            float2 x = xs[b * 64 + e];
            float a = wrs[e * 64 + f], c = wis[e * 64 + f];
            yr = __builtin_fmaf(x.x, a, yr); yr = __builtin_fmaf(-x.y, c, yr);
            yi = __builtin_fmaf(x.x, c, yi); yi = __builtin_fmaf( x.y, a, yi);
        }
        Y[((size_t)b * 64 + j) * 512 + (size_t)(h * 64 + f)] = make_float2(yr, yi);
    }
}

// ---------------- synthesis with full w-symmetry: 1 rotator -> 4 output rows -------------------
//   out(l)      = F0+F1+F2+F3          out(l+2048) = F0-F1+F2-F3
//   out(l+1024) = (F0-F2)-(H1-H3)      out(l+3072) = (F0-F2)+(H1-H3)
__global__ __launch_bounds__(256, 2) void k_synth(const float2* __restrict__ Y,
                                                  const float2* __restrict__ trig,
                                                  float* __restrict__ out) {
    __shared__ __align__(16) float2 ys[64][64];  // 32 KB, pre-scaled

    const int tid = threadIdx.x;
    const int bi  = blockIdx.x;
    const int b   = bi >> 7;        // 16
    const int hft = (bi >> 4) & 7;  // 8
    const int lt  = bi & 15;        // 16

    const float invN = 1.0f / 4096.0f;
    const float2* yb = Y + (size_t)b * 64 * 512 + (size_t)hft * 64;
    for (int t = tid; t < 64 * 64; t += NTHREADS) {
        int j = t >> 6, cc = t & 63;
        float2 y = yb[(size_t)j * 512 + cc];
        if (j == 0) ys[0][cc] = make_float2(y.x * invN, 0.0f);
        else        ys[j][cc] = make_float2(y.x * (2.0f * invN), y.y * (2.0f * invN));
    }
    __syncthreads();

    const int r = tid >> 3;          // 0..31
    const int c = tid & 7;           // 0..7
    const int l0 = lt * 64 + r * 2;  // base l (v=0) in [0, 1024)

    float2 rot[2], w[2];
#pragma unroll
    for (int v = 0; v < 2; ++v) {
        w[v] = trig[(l0 + v) & 4095];
        rot[v] = make_float2(1.0f, 0.0f);
    }

    float F0[2][8], F1[2][8], F2[2][8], F3[2][8], H1[2][8], H3[2][8];
#pragma unroll
    for (int v = 0; v < 2; ++v)
#pragma unroll
        for (int u = 0; u < 8; ++u) {
            F0[v][u] = F1[v][u] = F2[v][u] = F3[v][u] = 0.0f;
            H1[v][u] = H3[v][u] = 0.0f;
        }

    // b128 LDS loads: yv[2k], yv[2k+1] are consecutive float2s at ys[j][c*2 + 16k]
#define LOAD_YV(JROW)                                                        \
    float2 yv[8];                                                            \
    _Pragma("unroll")                                                        \
    for (int k4 = 0; k4 < 4; ++k4) {                                         \
        const float4 t4 = *(const float4*)&ys[(JROW)][c * 2 + k4 * 16];      \
        yv[2 * k4]     = make_float2(t4.x, t4.y);                            \
        yv[2 * k4 + 1] = make_float2(t4.z, t4.w);                            \
    }

    for (int j = 0; j < 64; j += 4) {
        // j+0 (even) -> F0
        {
            LOAD_YV(j)
#pragma unroll
            for (int v = 0; v < 2; ++v) {
                const float cx = rot[v].x, sx = rot[v].y;
#pragma unroll
                for (int u = 0; u < 8; ++u) {
                    float a = F0[v][u];
                    a = __builtin_fmaf(cx, yv[u].x, a);
                    a = __builtin_fmaf(-sx, yv[u].y, a);
                    F0[v][u] = a;
                }
                float nx = __builtin_fmaf(rot[v].x, w[v].x, -(rot[v].y * w[v].y));
                float ny = __builtin_fmaf(rot[v].x, w[v].y,  (rot[v].y * w[v].x));
                rot[v] = make_float2(nx, ny);
            }
        }
        // j+1 (odd) -> F1, H1
        {
            LOAD_YV(j + 1)
#pragma unroll
            for (int v = 0; v < 2; ++v) {
                const float cx = rot[v].x, sx = rot[v].y;
#pragma unroll
                for (int u = 0; u < 8; ++u) {
                    float a = F1[v][u], g = H1[v][u];
                    a = __builtin_fmaf(cx, yv[u].x, a);
                    a = __builtin_fmaf(-sx, yv[u].y, a);
                    g = __builtin_fmaf(sx, yv[u].x, g);
                    g = __builtin_fmaf(cx, yv[u].y, g);
                    F1[v][u] = a; H1[v][u] = g;
                }
                float nx = __builtin_fmaf(rot[v].x, w[v].x, -(rot[v].y * w[v].y));
                float ny = __builtin_fmaf(rot[v].x, w[v].y,  (rot[v].y * w[v].x));
                rot[v] = make_float2(nx, ny);
            }
        }
        // j+2 (even) -> F2
        {
            LOAD_YV(j + 2)
#pragma unroll
            for (int v = 0; v < 2; ++v) {
                const float cx = rot[v].x, sx = rot[v].y;
#pragma unroll
                for (int u = 0; u < 8; ++u) {
                    float a = F2[v][u];
                    a = __builtin_fmaf(cx, yv[u].x, a);
                    a = __builtin_fmaf(-sx, yv[u].y, a);
                    F2[v][u] = a;
                }
                float nx = __builtin_fmaf(rot[v].x, w[v].x, -(rot[v].y * w[v].y));
                float ny = __builtin_fmaf(rot[v].x, w[v].y,  (rot[v].y * w[v].x));
                rot[v] = make_float2(nx, ny);
            }
        }
        // j+3 (odd) -> F3, H3
        {
            LOAD_YV(j + 3)
#pragma unroll
            for (int v = 0; v < 2; ++v) {
                const float cx = rot[v].x, sx = rot[v].y;
#pragma unroll
                for (int u = 0; u < 8; ++u) {
                    float a = F3[v][u], g = H3[v][u];
                    a = __builtin_fmaf(cx, yv[u].x, a);
                    a = __builtin_fmaf(-sx, yv[u].y, a);
                    g = __builtin_fmaf(sx, yv[u].x, g);
                    g = __builtin_fmaf(cx, yv[u].y, g);
                    F3[v][u] = a; H3[v][u] = g;
                }
                float nx = __builtin_fmaf(rot[v].x, w[v].x, -(rot[v].y * w[v].y));
                float ny = __builtin_fmaf(rot[v].x, w[v].y,  (rot[v].y * w[v].x));
                rot[v] = make_float2(nx, ny);
            }
        }
    }
#undef LOAD_YV

    // stores: 4 rows per (v): l0+v, +1024, +2048, +3072
#pragma unroll
    for (int v = 0; v < 2; ++v) {
        float* o0 = out + ((size_t)(b * 4096 + l0 + v)) * 512 + (size_t)hft * 64;
        float* o1 = o0 + (size_t)1024 * 512;
        float* o2 = o0 + (size_t)2048 * 512;
        float* o3 = o0 + (size_t)3072 * 512;
#pragma unroll
        for (int k = 0; k < 4; ++k) {
            float2 s0, s1, s2, s3;
#pragma unroll
            for (int d = 0; d < 2; ++d) {
                const int u = 2 * k + d;
                const float p = F0[v][u] + F2[v][u];
                const float m = F0[v][u] - F2[v][u];
                const float q = F1[v][u] + F3[v][u];
                const float hh = H3[v][u] - H1[v][u];
                ((float*)&s0)[d] = p + q;
                ((float*)&s2)[d] = p - q;
                ((float*)&s1)[d] = m + hh;
                ((float*)&s3)[d] = m - hh;
            }
            *(float2*)(o0 + k * 16 + c * 2) = s0;
            *(float2*)(o1 + k * 16 + c * 2) = s1;
            *(float2*)(o2 + k * 16 + c * 2) = s2;
            *(float2*)(o3 + k * 16 + c * 2) = s3;
        }
    }
}

// ---------------- launch ----------------
extern "C" void kernel_launch(void* const* d_in, const int* in_sizes, int n_in,
                              void* d_out, int out_size, void* d_ws, size_t ws_size,
                              hipStream_t stream) {
    const float* q  = (const float*)d_in[0];
    const float* wr = (const float*)d_in[3];
    const float* wi = (const float*)d_in[4];

    char* ws = (char*)d_ws;
    float2*             trig  = (float2*)(ws + 0);                  // 32 KB
    unsigned long long* score = (unsigned long long*)(ws + 32768);  // 16 KB
    int*                idx   = (int*)(ws + 49152);                 // 256 B
    float2*             Y     = (float2*)(ws + 65536);              // 4 MB

    // d_out triples as: transposed-q scratch T -> spectrum Xout (in-place) -> final output.
    float2* Xs = (float2*)d_out;

    hipMemsetAsync(score, 0, 2048 * sizeof(unsigned long long), stream);
    k_tables<<<16, 256, 0, stream>>>(trig);
    k_xpose<<<4096, 256, 0, stream>>>(q, Xs);          // (b:16, h:8, c5:32), 128-row tiles
    k_fft<<<1024, 256, 0, stream>>>(trig, Xs, score);  // 4 planes/block, prefetch pipeline
    k_topk<<<8, 256, 0, stream>>>(score, idx);         // 2048 candidates, 1/thread
    k_proj<<<512, 256, 0, stream>>>(Xs, wr, wi, idx, Y);
    k_synth<<<2048, 256, 0, stream>>>(Y, trig, (float*)d_out);  // (b:16, hft:8, lt:16)
}

// Round 14
// 249.688 us; speedup vs baseline: 1.2411x; 1.0151x over previous
//
#include <hip/hip_runtime.h>

// Problem constants: B=16, L=4096, H=8, E=64, K=64, F=2049 (rfft bins)
// Only bins m in [1,2048] matter (bin 0 excluded from top-k; out_ft uses slots 0..63).

#define NTHREADS 256

// LDS swizzle for the FFT working array: flips bits 1-3 by bits 4-6 (bijective, disjoint).
#define ZI(i) ((i) ^ ((((i) >> 4) & 7) << 1))

__device__ inline float2 f2add(float2 a, float2 b) { return make_float2(a.x + b.x, a.y + b.y); }
__device__ inline float2 f2sub(float2 a, float2 b) { return make_float2(a.x - b.x, a.y - b.y); }
// complex mul, exactly 4 VALU (mul, fma, mul, fma)
__device__ inline float2 cmulf(float2 a, float2 b) {
    return make_float2(__builtin_fmaf(a.x, b.x, -(a.y * b.y)),
                       __builtin_fmaf(a.x, b.y,  a.y * b.x));
}

// radix-8 DIT butterfly on 8 points (3 stages in registers).
__device__ inline void radix8(float2& u0, float2& u1, float2& u2, float2& u3,
                              float2& u4, float2& u5, float2& u6, float2& u7,
                              float2 wA, float2 wB, float2 wC) {
    float2 t1 = cmulf(wA, u1), t3 = cmulf(wA, u3), t5 = cmulf(wA, u5), t7 = cmulf(wA, u7);
    float2 a0 = f2add(u0, t1), a1 = f2sub(u0, t1);
    float2 a2 = f2add(u2, t3), a3 = f2sub(u2, t3);
    float2 a4 = f2add(u4, t5), a5 = f2sub(u4, t5);
    float2 a6 = f2add(u6, t7), a7 = f2sub(u6, t7);
    float2 s2 = cmulf(wB, a2), s3 = cmulf(wB, a3);
    float2 s6 = cmulf(wB, a6), s7 = cmulf(wB, a7);
    float2 b0 = f2add(a0, s2), b2 = f2sub(a0, s2);
    float2 b1 = make_float2(a1.x + s3.y, a1.y - s3.x);   // a1 + (-i)s3
    float2 b3 = make_float2(a1.x - s3.y, a1.y + s3.x);   // a1 - (-i)s3
    float2 b4 = f2add(a4, s6), b6 = f2sub(a4, s6);
    float2 b5 = make_float2(a5.x + s7.y, a5.y - s7.x);
    float2 b7 = make_float2(a5.x - s7.y, a5.y + s7.x);
    const float2 C8 = make_float2(0.70710678118654752f, -0.70710678118654752f);  // e^{-i pi/4}
    float2 wC1 = cmulf(wC, C8);
    float2 r4 = cmulf(wC, b4);
    float2 r5 = cmulf(wC1, b5);
    float2 r6t = cmulf(wC, b6);  float2 r6 = make_float2(r6t.y, -r6t.x);   // -i * wC * b6
    float2 r7t = cmulf(wC1, b7); float2 r7 = make_float2(r7t.y, -r7t.x);   // e^{-3i pi/4} wC b7
    u0 = f2add(b0, r4); u4 = f2sub(b0, r4);
    u1 = f2add(b1, r5); u5 = f2sub(b1, r5);
    u2 = f2add(b2, r6); u6 = f2sub(b2, r6);
    u3 = f2add(b3, r7); u7 = f2sub(b3, r7);
}

// ---------------- table kernel: trig[k] = (cos, sin)(2*pi*k/4096), f64-accurate ----------------
__global__ void k_tables(float2* __restrict__ trig) {
    int k = blockIdx.x * blockDim.x + threadIdx.x;
    if (k < 4096) {
        double th = (6.283185307179586476925286766559 * (double)k) / 4096.0;
        trig[k] = make_float2((float)cos(th), (float)sin(th));
    }
}

// ---------------- transpose + bit-reversal: q[b,l,h,e] -> T[(b,h,eo)][p][j] (float2) -----------
// 128-row tiles (33 KB LDS -> 4 blocks/CU). Block (b:16, h:8, c5:32).
__global__ __launch_bounds__(256) void k_xpose(const float* __restrict__ q,
                                               float2* __restrict__ T) {
    __shared__ float tile[128][65];  // 33 KB, padded (+1)

    const int tid = threadIdx.x;
    const int bi  = blockIdx.x;
    const int b   = bi >> 8;
    const int h   = (bi >> 5) & 7;
    const int c5  = bi & 31;

    const float* qb = q + ((size_t)b * 4096 * 512) + (size_t)h * 64;
#pragma unroll
    for (int i = 0; i < 8; ++i) {
        const int f = tid + 256 * i;
        const int t = f >> 4, e4 = f & 15;
        const float4 v = *(const float4*)(qb + (size_t)(c5 + 32 * t) * 512 + e4 * 4);
        tile[t][e4 * 4 + 0] = v.x;
        tile[t][e4 * 4 + 1] = v.y;
        tile[t][e4 * 4 + 2] = v.z;
        tile[t][e4 * 4 + 3] = v.w;
    }
    __syncthreads();

    const int wave = tid >> 6, lane = tid & 63;
    const int rl  = __brev(lane) >> 26;  // rev6(lane)
    const int r5c = __brev(c5) >> 27;    // rev5(c5)
    for (int cc = wave; cc < 32; cc += 4) {
        const int eo = cc >> 2, p = cc & 3;
        const int col0 = eo * 8 + 2 * p;
        float2* dst = T + ((size_t)((b * 8 + h) * 8 + eo)) * 16384 + (size_t)p * 4096
                        + (size_t)r5c * 128;
        float4 o;
        o.x = tile[rl][col0];      o.y = tile[rl][col0 + 1];
        o.z = tile[rl + 64][col0]; o.w = tile[rl + 64][col0 + 1];
        *(float4*)(dst + 2 * lane) = o;  // 16B/lane, contiguous 1KB run per (eo,p)
    }
}

// ---------------- FFT (4 x radix-8 passes) + spectrum store + score accumulation ----------------
// R11 structure (1024 blocks, 4-plane register-prefetch pipeline, eacc in registers).
// Pass-3 twiddles read directly from global trig (L1-resident) -> LDS 33.7KB.
__global__ __launch_bounds__(256) void k_fft(const float2* __restrict__ trig,
                                             float2* __restrict__ Xout,
                                             unsigned long long* __restrict__ score) {
    __shared__ float2 z[4096];     // 32 KB (swizzled indexing)
    __shared__ float2 ctw[216];    // 1.7 KB: [0,24) pass1 triples, [24,216) pass2 triples

    const int tid = threadIdx.x;
    const int bi  = blockIdx.x;

    // build compact twiddle triples for passes 1-2 only
    if (tid < 72) {
        int off, j, sA;
        if (tid < 8) { off = 0;  j = tid;     sA = 8; }   // pass1 (st=4, h=8,  j<8)
        else         { off = 24; j = tid - 8; sA = 5; }   // pass2 (st=7, h=64, j<64)
        float2 a = trig[j << sA], b = trig[j << (sA - 1)], c = trig[j << (sA - 2)];
        ctw[off + 3 * j + 0] = make_float2(a.x, -a.y);
        ctw[off + 3 * j + 1] = make_float2(b.x, -b.y);
        ctw[off + 3 * j + 2] = make_float2(c.x, -c.y);
    }

    float eaccr[8];
#pragma unroll
    for (int k = 0; k < 8; ++k) eaccr[k] = 0.f;

    const float2 ONE = make_float2(1.0f, 0.0f);
    const float2* base = Xout + (size_t)bi * 16384;

    // prefetch plane 0 into registers (2 items/thread x 4 float4)
    float4 pre[2][4];
#pragma unroll
    for (int it = 0; it < 2; ++it) {
        const int t = tid + 256 * it;
#pragma unroll
        for (int g = 0; g < 4; ++g) pre[it][g] = *(const float4*)(base + 8 * t + 2 * g);
    }
    __syncthreads();  // ctw ready

    for (int p = 0; p < 4; ++p) {
        // move prefetched data to cur, then immediately issue next plane's loads
        float4 cur[2][4];
#pragma unroll
        for (int it = 0; it < 2; ++it)
#pragma unroll
            for (int g = 0; g < 4; ++g) cur[it][g] = pre[it][g];

        if (p < 3) {
            const float2* pn = base + (size_t)(p + 1) * 4096;
#pragma unroll
            for (int it = 0; it < 2; ++it) {
                const int t = tid + 256 * it;
#pragma unroll
                for (int g = 0; g < 4; ++g) pre[it][g] = *(const float4*)(pn + 8 * t + 2 * g);
            }
        }

        // pass 0 (stages 1-3, unit twiddles) on registers; store swizzled to LDS
#pragma unroll
        for (int it = 0; it < 2; ++it) {
            const int t = tid + 256 * it;
            float2 u0 = make_float2(cur[it][0].x, cur[it][0].y);
            float2 u1 = make_float2(cur[it][0].z, cur[it][0].w);
            float2 u2 = make_float2(cur[it][1].x, cur[it][1].y);
            float2 u3 = make_float2(cur[it][1].z, cur[it][1].w);
            float2 u4 = make_float2(cur[it][2].x, cur[it][2].y);
            float2 u5 = make_float2(cur[it][2].z, cur[it][2].w);
            float2 u6 = make_float2(cur[it][3].x, cur[it][3].y);
            float2 u7 = make_float2(cur[it][3].z, cur[it][3].w);
            radix8(u0, u1, u2, u3, u4, u5, u6, u7, ONE, ONE, ONE);
            const int i0 = 8 * t;
            z[ZI(i0 + 0)] = u0; z[ZI(i0 + 1)] = u1; z[ZI(i0 + 2)] = u2; z[ZI(i0 + 3)] = u3;
            z[ZI(i0 + 4)] = u4; z[ZI(i0 + 5)] = u5; z[ZI(i0 + 6)] = u6; z[ZI(i0 + 7)] = u7;
        }
        __syncthreads();

        // passes 1..3: stages (4,5,6), (7,8,9), (10,11,12); h = 8, 64, 512
#pragma unroll
        for (int p8 = 1; p8 <= 3; ++p8) {
            const int st  = 1 + 3 * p8;
            const int h   = 1 << (st - 1);
            for (int t = tid; t < 512; t += NTHREADS) {
                const int j = t & (h - 1);
                const int g = t >> (st - 1);
                const int i0 = (g << (st + 2)) + j;
                int a0 = ZI(i0),         a1 = ZI(i0 + h),     a2 = ZI(i0 + 2 * h), a3 = ZI(i0 + 3 * h);
                int a4 = ZI(i0 + 4 * h), a5 = ZI(i0 + 5 * h), a6 = ZI(i0 + 6 * h), a7 = ZI(i0 + 7 * h);
                float2 u0 = z[a0], u1 = z[a1], u2 = z[a2], u3 = z[a3];
                float2 u4 = z[a4], u5 = z[a5], u6 = z[a6], u7 = z[a7];
                float2 wA, wB, wC;
                if (p8 < 3) {
                    const int off = (p8 == 1) ? 0 : 24;
                    wA = ctw[off + 3 * j + 0];
                    wB = ctw[off + 3 * j + 1];
                    wC = ctw[off + 3 * j + 2];
                } else {
                    // pass3: read from global trig (L1-resident), conj inline
                    float2 a = trig[j << 2], b = trig[j << 1], c = trig[j];
                    wA = make_float2(a.x, -a.y);
                    wB = make_float2(b.x, -b.y);
                    wC = make_float2(c.x, -c.y);
                }
                radix8(u0, u1, u2, u3, u4, u5, u6, u7, wA, wB, wC);
                z[a0] = u0; z[a1] = u1; z[a2] = u2; z[a3] = u3;
                z[a4] = u4; z[a5] = u5; z[a6] = u6; z[a7] = u7;
            }
            __syncthreads();
        }

        // unpack two real spectra; store (overwrites this pair's own plane); accumulate energy
        {
            const size_t s0 = (size_t)bi * 16384 + (size_t)p * 4096;  // = signal (bi*8+2p) * 2048
#pragma unroll
            for (int k = 0; k < 8; ++k) {
                const int t = tid + 256 * k;
                const int m = t + 1;
                float2 Za = z[ZI(m)];
                float2 Zb = z[ZI(4096 - m)];
                float Xr0 = 0.5f * (Za.x + Zb.x);
                float Xi0 = 0.5f * (Za.y - Zb.y);
                float Xr1 = 0.5f * (Za.y + Zb.y);
                float Xi1 = 0.5f * (Zb.x - Za.x);
                Xout[s0 + t]        = make_float2(Xr0, Xi0);
                Xout[s0 + 2048 + t] = make_float2(Xr1, Xi1);
                eaccr[k] += Xr0 * Xr0 + Xi0 * Xi0 + Xr1 * Xr1 + Xi1 * Xi1;
            }
        }
        __syncthreads();  // protect z before next plane's pass-0 stores
    }

    // deterministic reduction: fixed-point u64 atomics (integer adds commute exactly)
#pragma unroll
    for (int k = 0; k < 8; ++k) {
        unsigned long long v = (unsigned long long)llrintf(eaccr[k] * 1048576.0f);  // 2^20
        atomicAdd(&score[tid + 256 * k], v);
    }
}

// ---------------- top-64, parallelized: 8 blocks x 256 threads, one candidate per thread -------
__global__ __launch_bounds__(256) void k_topk(const unsigned long long* __restrict__ score,
                                              int* __restrict__ idx) {
    __shared__ unsigned long long s[2048];
    const int tid = threadIdx.x;
    for (int t = tid; t < 2048; t += 256) s[t] = score[t];
    __syncthreads();

    const int t = blockIdx.x * 256 + tid;  // 0..2047
    const unsigned long long my = s[t];
    int rank = 0;
#pragma unroll 8
    for (int u = 0; u < 2048; ++u) {
        unsigned long long o = s[u];
        rank += (int)((o > my) || (o == my && u < t));
    }
    if (rank < 64) idx[rank] = t + 1;  // store frequency index m
}

// ---------------- gather + complex projection: Y[b,j,h,f] = sum_e X[b,idx_j,h,e] * W[j,h,e,f] ----
__global__ __launch_bounds__(256) void k_proj(const float2* __restrict__ X,
                                              const float* __restrict__ wr,
                                              const float* __restrict__ wi,
                                              const int* __restrict__ idx,
                                              float2* __restrict__ Y) {
    __shared__ float2 xs[16 * 64];   // [b][e]  8 KB
    __shared__ float  wrs[64 * 64];  // [e][f] 16 KB
    __shared__ float  wis[64 * 64];  // 16 KB

    const int tid = threadIdx.x;
    const int j = blockIdx.x >> 3;
    const int h = blockIdx.x & 7;
    const int m = idx[j];

    for (int t = tid; t < 1024; t += NTHREADS) {
        int b = t >> 6, e = t & 63;
        xs[t] = X[((size_t)((b * 8 + h) * 64 + e)) * 2048 + (size_t)(m - 1)];
    }
    const float* wrb = wr + ((size_t)(j * 8 + h)) * 4096;
    const float* wib = wi + ((size_t)(j * 8 + h)) * 4096;
    for (int t = tid; t < 4096; t += NTHREADS) { wrs[t] = wrb[t]; wis[t] = wib[t]; }
    __syncthreads();

    const int b  = tid >> 4;   // 0..15
    const int fg = tid & 15;   // 0..15
    for (int fo = 0; fo < 4; ++fo) {
        int f = fg * 4 + fo;
        float yr = 0.f, yi = 0.f;
        for (int e = 0; e < 64; ++e) {
            float2 x = xs[b * 64 + e];
            float a = wrs[e * 64 + f], c = wis[e * 64 + f];
            yr = __builtin_fmaf(x.x, a, yr); yr = __builtin_fmaf(-x.y, c, yr);
            yi = __builtin_fmaf(x.x, c, yi); yi = __builtin_fmaf( x.y, a, yi);
        }
        Y[((size_t)b * 64 + j) * 512 + (size_t)(h * 64 + f)] = make_float2(yr, yi);
    }
}

// ---------------- synthesis with full w-symmetry: 1 rotator -> 4 output rows -------------------
//   out(l)      = F0+F1+F2+F3          out(l+2048) = F0-F1+F2-F3
//   out(l+1024) = (F0-F2)-(H1-H3)      out(l+3072) = (F0-F2)+(H1-H3)
// hf-tile 32 (16 KB LDS), per-thread 2 base-l x 4 hf -> 48 accumulators (no spill pressure).
// grid: 4096 blocks = (b:16, hft:16, lt:16). Threads: r = tid>>3 (0..31), c = tid&7 (0..7).
__global__ __launch_bounds__(256, 4) void k_synth(const float2* __restrict__ Y,
                                                  const float2* __restrict__ trig,
                                                  float* __restrict__ out) {
    __shared__ __align__(16) float2 ys[64][32];  // 16 KB, pre-scaled

    const int tid = threadIdx.x;
    const int bi  = blockIdx.x;
    const int b   = bi >> 8;         // 16
    const int hft = (bi >> 4) & 15;  // 16
    const int lt  = bi & 15;         // 16

    const float invN = 1.0f / 4096.0f;
    const float2* yb = Y + (size_t)b * 64 * 512 + (size_t)hft * 32;
    for (int t = tid; t < 64 * 32; t += NTHREADS) {
        int j = t >> 5, cc = t & 31;
        float2 y = yb[(size_t)j * 512 + cc];
        if (j == 0) ys[0][cc] = make_float2(y.x * invN, 0.0f);
        else        ys[j][cc] = make_float2(y.x * (2.0f * invN), y.y * (2.0f * invN));
    }
    __syncthreads();

    const int r = tid >> 3;          // 0..31
    const int c = tid & 7;           // 0..7
    const int l0 = lt * 64 + r * 2;  // base l (v=0) in [0, 1024)

    float2 rot[2], w[2];
#pragma unroll
    for (int v = 0; v < 2; ++v) {
        w[v] = trig[(l0 + v) & 4095];
        rot[v] = make_float2(1.0f, 0.0f);
    }

    float F0[2][4], F1[2][4], F2[2][4], F3[2][4], H1[2][4], H3[2][4];
#pragma unroll
    for (int v = 0; v < 2; ++v)
#pragma unroll
        for (int u = 0; u < 4; ++u) {
            F0[v][u] = F1[v][u] = F2[v][u] = F3[v][u] = 0.0f;
            H1[v][u] = H3[v][u] = 0.0f;
        }

    // cols per thread: u=0,1 -> c*2, c*2+1 ; u=2,3 -> c*2+16, c*2+17 (two b128 loads, no conflict)
#define LOAD_YV(JROW)                                                        \
    float2 yv[4];                                                            \
    {                                                                        \
        const float4 ta = *(const float4*)&ys[(JROW)][c * 2];                \
        const float4 tb = *(const float4*)&ys[(JROW)][c * 2 + 16];           \
        yv[0] = make_float2(ta.x, ta.y); yv[1] = make_float2(ta.z, ta.w);    \
        yv[2] = make_float2(tb.x, tb.y); yv[3] = make_float2(tb.z, tb.w);    \
    }

    for (int j = 0; j < 64; j += 4) {
        // j+0 (even) -> F0
        {
            LOAD_YV(j)
#pragma unroll
            for (int v = 0; v < 2; ++v) {
                const float cx = rot[v].x, sx = rot[v].y;
#pragma unroll
                for (int u = 0; u < 4; ++u) {
                    float a = F0[v][u];
                    a = __builtin_fmaf(cx, yv[u].x, a);
                    a = __builtin_fmaf(-sx, yv[u].y, a);
                    F0[v][u] = a;
                }
                float nx = __builtin_fmaf(rot[v].x, w[v].x, -(rot[v].y * w[v].y));
                float ny = __builtin_fmaf(rot[v].x, w[v].y,  (rot[v].y * w[v].x));
                rot[v] = make_float2(nx, ny);
            }
        }
        // j+1 (odd) -> F1, H1
        {
            LOAD_YV(j + 1)
#pragma unroll
            for (int v = 0; v < 2; ++v) {
                const float cx = rot[v].x, sx = rot[v].y;
#pragma unroll
                for (int u = 0; u < 4; ++u) {
                    float a = F1[v][u], g = H1[v][u];
                    a = __builtin_fmaf(cx, yv[u].x, a);
                    a = __builtin_fmaf(-sx, yv[u].y, a);
                    g = __builtin_fmaf(sx, yv[u].x, g);
                    g = __builtin_fmaf(cx, yv[u].y, g);
                    F1[v][u] = a; H1[v][u] = g;
                }
                float nx = __builtin_fmaf(rot[v].x, w[v].x, -(rot[v].y * w[v].y));
                float ny = __builtin_fmaf(rot[v].x, w[v].y,  (rot[v].y * w[v].x));
                rot[v] = make_float2(nx, ny);
            }
        }
        // j+2 (even) -> F2
        {
            LOAD_YV(j + 2)
#pragma unroll
            for (int v = 0; v < 2; ++v) {
                const float cx = rot[v].x, sx = rot[v].y;
#pragma unroll
                for (int u = 0; u < 4; ++u) {
                    float a = F2[v][u];
                    a = __builtin_fmaf(cx, yv[u].x, a);
                    a = __builtin_fmaf(-sx, yv[u].y, a);
                    F2[v][u] = a;
                }
                float nx = __builtin_fmaf(rot[v].x, w[v].x, -(rot[v].y * w[v].y));
                float ny = __builtin_fmaf(rot[v].x, w[v].y,  (rot[v].y * w[v].x));
                rot[v] = make_float2(nx, ny);
            }
        }
        // j+3 (odd) -> F3, H3
        {
            LOAD_YV(j + 3)
#pragma unroll
            for (int v = 0; v < 2; ++v) {
                const float cx = rot[v].x, sx = rot[v].y;
#pragma unroll
                for (int u = 0; u < 4; ++u) {
                    float a = F3[v][u], g = H3[v][u];
                    a = __builtin_fmaf(cx, yv[u].x, a);
                    a = __builtin_fmaf(-sx, yv[u].y, a);
                    g = __builtin_fmaf(sx, yv[u].x, g);
                    g = __builtin_fmaf(cx, yv[u].y, g);
                    F3[v][u] = a; H3[v][u] = g;
                }
                float nx = __builtin_fmaf(rot[v].x, w[v].x, -(rot[v].y * w[v].y));
                float ny = __builtin_fmaf(rot[v].x, w[v].y,  (rot[v].y * w[v].x));
                rot[v] = make_float2(nx, ny);
            }
        }
    }
#undef LOAD_YV

    // stores: 4 rows per (v): l0+v, +1024, +2048, +3072; cols k*16 + c*2 (+1)
#pragma unroll
    for (int v = 0; v < 2; ++v) {
        float* o0 = out + ((size_t)(b * 4096 + l0 + v)) * 512 + (size_t)hft * 32;
        float* o1 = o0 + (size_t)1024 * 512;
        float* o2 = o0 + (size_t)2048 * 512;
        float* o3 = o0 + (size_t)3072 * 512;
#pragma unroll
        for (int k = 0; k < 2; ++k) {
            float2 s0, s1, s2, s3;
#pragma unroll
            for (int d = 0; d < 2; ++d) {
                const int u = 2 * k + d;
                const float p = F0[v][u] + F2[v][u];
                const float m = F0[v][u] - F2[v][u];
                const float q = F1[v][u] + F3[v][u];
                const float hh = H3[v][u] - H1[v][u];
                ((float*)&s0)[d] = p + q;
                ((float*)&s2)[d] = p - q;
                ((float*)&s1)[d] = m + hh;
                ((float*)&s3)[d] = m - hh;
            }
            *(float2*)(o0 + k * 16 + c * 2) = s0;
            *(float2*)(o1 + k * 16 + c * 2) = s1;
            *(float2*)(o2 + k * 16 + c * 2) = s2;
            *(float2*)(o3 + k * 16 + c * 2) = s3;
        }
    }
}

// ---------------- launch ----------------
extern "C" void kernel_launch(void* const* d_in, const int* in_sizes, int n_in,
                              void* d_out, int out_size, void* d_ws, size_t ws_size,
                              hipStream_t stream) {
    const float* q  = (const float*)d_in[0];
    const float* wr = (const float*)d_in[3];
    const float* wi = (const float*)d_in[4];

    char* ws = (char*)d_ws;
    float2*             trig  = (float2*)(ws + 0);                  // 32 KB
    unsigned long long* score = (unsigned long long*)(ws + 32768);  // 16 KB
    int*                idx   = (int*)(ws + 49152);                 // 256 B
    float2*             Y     = (float2*)(ws + 65536);              // 4 MB

    // d_out triples as: transposed-q scratch T -> spectrum Xout (in-place) -> final output.
    float2* Xs = (float2*)d_out;

    hipMemsetAsync(score, 0, 2048 * sizeof(unsigned long long), stream);
    k_tables<<<16, 256, 0, stream>>>(trig);
    k_xpose<<<4096, 256, 0, stream>>>(q, Xs);          // (b:16, h:8, c5:32), 128-row tiles
    k_fft<<<1024, 256, 0, stream>>>(trig, Xs, score);  // 4 planes/block, prefetch pipeline
    k_topk<<<8, 256, 0, stream>>>(score, idx);         // 2048 candidates, 1/thread
    k_proj<<<512, 256, 0, stream>>>(Xs, wr, wi, idx, Y);
    k_synth<<<4096, 256, 0, stream>>>(Y, trig, (float*)d_out);  // (b:16, hft:16, lt:16)
}

// Round 15
// 249.617 us; speedup vs baseline: 1.2414x; 1.0003x over previous
//
#include <hip/hip_runtime.h>

// Problem constants: B=16, L=4096, H=8, E=64, K=64, F=2049 (rfft bins)
// Only bins m in [1,2048] matter (bin 0 excluded from top-k; out_ft uses slots 0..63).

#define NTHREADS 256

// LDS-only barrier: drains LDS ops (lgkmcnt) but leaves global loads/stores in flight.
// Safe when the barrier only orders LDS producer->consumer (no cross-wave global comm).
// This avoids the __syncthreads() vmcnt(0) drain that serializes global traffic (m97).
__device__ inline void lds_barrier() {
    asm volatile("s_waitcnt lgkmcnt(0)" ::: "memory");
    __builtin_amdgcn_s_barrier();
}

// LDS swizzle for the FFT working array: flips bits 1-3 by bits 4-6 (bijective, disjoint).
#define ZI(i) ((i) ^ ((((i) >> 4) & 7) << 1))

__device__ inline float2 f2add(float2 a, float2 b) { return make_float2(a.x + b.x, a.y + b.y); }
__device__ inline float2 f2sub(float2 a, float2 b) { return make_float2(a.x - b.x, a.y - b.y); }
// complex mul, exactly 4 VALU (mul, fma, mul, fma)
__device__ inline float2 cmulf(float2 a, float2 b) {
    return make_float2(__builtin_fmaf(a.x, b.x, -(a.y * b.y)),
                       __builtin_fmaf(a.x, b.y,  a.y * b.x));
}

// radix-8 DIT butterfly on 8 points (3 stages in registers).
__device__ inline void radix8(float2& u0, float2& u1, float2& u2, float2& u3,
                              float2& u4, float2& u5, float2& u6, float2& u7,
                              float2 wA, float2 wB, float2 wC) {
    float2 t1 = cmulf(wA, u1), t3 = cmulf(wA, u3), t5 = cmulf(wA, u5), t7 = cmulf(wA, u7);
    float2 a0 = f2add(u0, t1), a1 = f2sub(u0, t1);
    float2 a2 = f2add(u2, t3), a3 = f2sub(u2, t3);
    float2 a4 = f2add(u4, t5), a5 = f2sub(u4, t5);
    float2 a6 = f2add(u6, t7), a7 = f2sub(u6, t7);
    float2 s2 = cmulf(wB, a2), s3 = cmulf(wB, a3);
    float2 s6 = cmulf(wB, a6), s7 = cmulf(wB, a7);
    float2 b0 = f2add(a0, s2), b2 = f2sub(a0, s2);
    float2 b1 = make_float2(a1.x + s3.y, a1.y - s3.x);   // a1 + (-i)s3
    float2 b3 = make_float2(a1.x - s3.y, a1.y + s3.x);   // a1 - (-i)s3
    float2 b4 = f2add(a4, s6), b6 = f2sub(a4, s6);
    float2 b5 = make_float2(a5.x + s7.y, a5.y - s7.x);
    float2 b7 = make_float2(a5.x - s7.y, a5.y + s7.x);
    const float2 C8 = make_float2(0.70710678118654752f, -0.70710678118654752f);  // e^{-i pi/4}
    float2 wC1 = cmulf(wC, C8);
    float2 r4 = cmulf(wC, b4);
    float2 r5 = cmulf(wC1, b5);
    float2 r6t = cmulf(wC, b6);  float2 r6 = make_float2(r6t.y, -r6t.x);   // -i * wC * b6
    float2 r7t = cmulf(wC1, b7); float2 r7 = make_float2(r7t.y, -r7t.x);   // e^{-3i pi/4} wC b7
    u0 = f2add(b0, r4); u4 = f2sub(b0, r4);
    u1 = f2add(b1, r5); u5 = f2sub(b1, r5);
    u2 = f2add(b2, r6); u6 = f2sub(b2, r6);
    u3 = f2add(b3, r7); u7 = f2sub(b3, r7);
}

// ---------------- table kernel: trig[k] = (cos, sin)(2*pi*k/4096), f64-accurate ----------------
__global__ void k_tables(float2* __restrict__ trig) {
    int k = blockIdx.x * blockDim.x + threadIdx.x;
    if (k < 4096) {
        double th = (6.283185307179586476925286766559 * (double)k) / 4096.0;
        trig[k] = make_float2((float)cos(th), (float)sin(th));
    }
}

// ---------------- transpose + bit-reversal: q[b,l,h,e] -> T[(b,h,eo)][p][j] (float2) -----------
// 128-row tiles (33 KB LDS -> 4 blocks/CU). Block (b:16, h:8, c5:32).
__global__ __launch_bounds__(256) void k_xpose(const float* __restrict__ q,
                                               float2* __restrict__ T) {
    __shared__ float tile[128][65];  // 33 KB, padded (+1)

    const int tid = threadIdx.x;
    const int bi  = blockIdx.x;
    const int b   = bi >> 8;
    const int h   = (bi >> 5) & 7;
    const int c5  = bi & 31;

    const float* qb = q + ((size_t)b * 4096 * 512) + (size_t)h * 64;
#pragma unroll
    for (int i = 0; i < 8; ++i) {
        const int f = tid + 256 * i;
        const int t = f >> 4, e4 = f & 15;
        const float4 v = *(const float4*)(qb + (size_t)(c5 + 32 * t) * 512 + e4 * 4);
        tile[t][e4 * 4 + 0] = v.x;
        tile[t][e4 * 4 + 1] = v.y;
        tile[t][e4 * 4 + 2] = v.z;
        tile[t][e4 * 4 + 3] = v.w;
    }
    lds_barrier();

    const int wave = tid >> 6, lane = tid & 63;
    const int rl  = __brev(lane) >> 26;  // rev6(lane)
    const int r5c = __brev(c5) >> 27;    // rev5(c5)
    for (int cc = wave; cc < 32; cc += 4) {
        const int eo = cc >> 2, p = cc & 3;
        const int col0 = eo * 8 + 2 * p;
        float2* dst = T + ((size_t)((b * 8 + h) * 8 + eo)) * 16384 + (size_t)p * 4096
                        + (size_t)r5c * 128;
        float4 o;
        o.x = tile[rl][col0];      o.y = tile[rl][col0 + 1];
        o.z = tile[rl + 64][col0]; o.w = tile[rl + 64][col0 + 1];
        *(float4*)(dst + 2 * lane) = o;  // 16B/lane, contiguous 1KB run per (eo,p)
    }
}

// ---------------- FFT (4 x radix-8 passes) + spectrum store + score accumulation ----------------
// 1024 blocks, 4-plane register-prefetch pipeline, eacc in registers, pass-3 twiddles from
// global trig. All plane-loop barriers are LDS-only (lgkmcnt) so the plane-(p+1) prefetch
// loads and the plane-p spectrum stores stay in flight across barriers.
__global__ __launch_bounds__(256) void k_fft(const float2* __restrict__ trig,
                                             float2* __restrict__ Xout,
                                             unsigned long long* __restrict__ score) {
    __shared__ float2 z[4096];     // 32 KB (swizzled indexing)
    __shared__ float2 ctw[216];    // 1.7 KB: [0,24) pass1 triples, [24,216) pass2 triples

    const int tid = threadIdx.x;
    const int bi  = blockIdx.x;

    // build compact twiddle triples for passes 1-2 only
    if (tid < 72) {
        int off, j, sA;
        if (tid < 8) { off = 0;  j = tid;     sA = 8; }   // pass1 (st=4, h=8,  j<8)
        else         { off = 24; j = tid - 8; sA = 5; }   // pass2 (st=7, h=64, j<64)
        float2 a = trig[j << sA], b = trig[j << (sA - 1)], c = trig[j << (sA - 2)];
        ctw[off + 3 * j + 0] = make_float2(a.x, -a.y);
        ctw[off + 3 * j + 1] = make_float2(b.x, -b.y);
        ctw[off + 3 * j + 2] = make_float2(c.x, -c.y);
    }

    float eaccr[8];
#pragma unroll
    for (int k = 0; k < 8; ++k) eaccr[k] = 0.f;

    const float2 ONE = make_float2(1.0f, 0.0f);
    const float2* base = Xout + (size_t)bi * 16384;

    // prefetch plane 0 into registers (2 items/thread x 4 float4)
    float4 pre[2][4];
#pragma unroll
    for (int it = 0; it < 2; ++it) {
        const int t = tid + 256 * it;
#pragma unroll
        for (int g = 0; g < 4; ++g) pre[it][g] = *(const float4*)(base + 8 * t + 2 * g);
    }
    lds_barrier();  // ctw ready (prefetch loads stay in flight)

    for (int p = 0; p < 4; ++p) {
        // move prefetched data to cur (compiler inserts vmcnt wait), issue next plane's loads
        float4 cur[2][4];
#pragma unroll
        for (int it = 0; it < 2; ++it)
#pragma unroll
            for (int g = 0; g < 4; ++g) cur[it][g] = pre[it][g];

        if (p < 3) {
            const float2* pn = base + (size_t)(p + 1) * 4096;
#pragma unroll
            for (int it = 0; it < 2; ++it) {
                const int t = tid + 256 * it;
#pragma unroll
                for (int g = 0; g < 4; ++g) pre[it][g] = *(const float4*)(pn + 8 * t + 2 * g);
            }
        }

        // pass 0 (stages 1-3, unit twiddles) on registers; store swizzled to LDS
#pragma unroll
        for (int it = 0; it < 2; ++it) {
            const int t = tid + 256 * it;
            float2 u0 = make_float2(cur[it][0].x, cur[it][0].y);
            float2 u1 = make_float2(cur[it][0].z, cur[it][0].w);
            float2 u2 = make_float2(cur[it][1].x, cur[it][1].y);
            float2 u3 = make_float2(cur[it][1].z, cur[it][1].w);
            float2 u4 = make_float2(cur[it][2].x, cur[it][2].y);
            float2 u5 = make_float2(cur[it][2].z, cur[it][2].w);
            float2 u6 = make_float2(cur[it][3].x, cur[it][3].y);
            float2 u7 = make_float2(cur[it][3].z, cur[it][3].w);
            radix8(u0, u1, u2, u3, u4, u5, u6, u7, ONE, ONE, ONE);
            const int i0 = 8 * t;
            z[ZI(i0 + 0)] = u0; z[ZI(i0 + 1)] = u1; z[ZI(i0 + 2)] = u2; z[ZI(i0 + 3)] = u3;
            z[ZI(i0 + 4)] = u4; z[ZI(i0 + 5)] = u5; z[ZI(i0 + 6)] = u6; z[ZI(i0 + 7)] = u7;
        }
        lds_barrier();

        // passes 1..3: stages (4,5,6), (7,8,9), (10,11,12); h = 8, 64, 512
#pragma unroll
        for (int p8 = 1; p8 <= 3; ++p8) {
            const int st  = 1 + 3 * p8;
            const int h   = 1 << (st - 1);
            for (int t = tid; t < 512; t += NTHREADS) {
                const int j = t & (h - 1);
                const int g = t >> (st - 1);
                const int i0 = (g << (st + 2)) + j;
                int a0 = ZI(i0),         a1 = ZI(i0 + h),     a2 = ZI(i0 + 2 * h), a3 = ZI(i0 + 3 * h);
                int a4 = ZI(i0 + 4 * h), a5 = ZI(i0 + 5 * h), a6 = ZI(i0 + 6 * h), a7 = ZI(i0 + 7 * h);
                float2 u0 = z[a0], u1 = z[a1], u2 = z[a2], u3 = z[a3];
                float2 u4 = z[a4], u5 = z[a5], u6 = z[a6], u7 = z[a7];
                float2 wA, wB, wC;
                if (p8 < 3) {
                    const int off = (p8 == 1) ? 0 : 24;
                    wA = ctw[off + 3 * j + 0];
                    wB = ctw[off + 3 * j + 1];
                    wC = ctw[off + 3 * j + 2];
                } else {
                    // pass3: read from global trig (L1-resident), conj inline
                    float2 a = trig[j << 2], b = trig[j << 1], c = trig[j];
                    wA = make_float2(a.x, -a.y);
                    wB = make_float2(b.x, -b.y);
                    wC = make_float2(c.x, -c.y);
                }
                radix8(u0, u1, u2, u3, u4, u5, u6, u7, wA, wB, wC);
                z[a0] = u0; z[a1] = u1; z[a2] = u2; z[a3] = u3;
                z[a4] = u4; z[a5] = u5; z[a6] = u6; z[a7] = u7;
            }
            lds_barrier();
        }

        // unpack two real spectra; store (overwrites this pair's own plane); accumulate energy
        {
            const size_t s0 = (size_t)bi * 16384 + (size_t)p * 4096;  // = signal (bi*8+2p) * 2048
#pragma unroll
            for (int k = 0; k < 8; ++k) {
                const int t = tid + 256 * k;
                const int m = t + 1;
                float2 Za = z[ZI(m)];
                float2 Zb = z[ZI(4096 - m)];
                float Xr0 = 0.5f * (Za.x + Zb.x);
                float Xi0 = 0.5f * (Za.y - Zb.y);
                float Xr1 = 0.5f * (Za.y + Zb.y);
                float Xi1 = 0.5f * (Zb.x - Za.x);
                Xout[s0 + t]        = make_float2(Xr0, Xi0);
                Xout[s0 + 2048 + t] = make_float2(Xr1, Xi1);
                eaccr[k] += Xr0 * Xr0 + Xi0 * Xi0 + Xr1 * Xr1 + Xi1 * Xi1;
            }
        }
        lds_barrier();  // z reads done; stores drain lazily under next plane's compute
    }

    // deterministic reduction: fixed-point u64 atomics (integer adds commute exactly)
#pragma unroll
    for (int k = 0; k < 8; ++k) {
        unsigned long long v = (unsigned long long)llrintf(eaccr[k] * 1048576.0f);  // 2^20
        atomicAdd(&score[tid + 256 * k], v);
    }
}

// ---------------- top-64, parallelized: 8 blocks x 256 threads, one candidate per thread -------
__global__ __launch_bounds__(256) void k_topk(const unsigned long long* __restrict__ score,
                                              int* __restrict__ idx) {
    __shared__ unsigned long long s[2048];
    const int tid = threadIdx.x;
    for (int t = tid; t < 2048; t += 256) s[t] = score[t];
    __syncthreads();

    const int t = blockIdx.x * 256 + tid;  // 0..2047
    const unsigned long long my = s[t];
    int rank = 0;
#pragma unroll 8
    for (int u = 0; u < 2048; ++u) {
        unsigned long long o = s[u];
        rank += (int)((o > my) || (o == my && u < t));
    }
    if (rank < 64) idx[rank] = t + 1;  // store frequency index m
}

// ---------------- gather + complex projection: Y[b,j,h,f] = sum_e X[b,idx_j,h,e] * W[j,h,e,f] ----
__global__ __launch_bounds__(256) void k_proj(const float2* __restrict__ X,
                                              const float* __restrict__ wr,
                                              const float* __restrict__ wi,
                                              const int* __restrict__ idx,
                                              float2* __restrict__ Y) {
    __shared__ float2 xs[16 * 64];   // [b][e]  8 KB
    __shared__ float  wrs[64 * 64];  // [e][f] 16 KB
    __shared__ float  wis[64 * 64];  // 16 KB

    const int tid = threadIdx.x;
    const int j = blockIdx.x >> 3;
    const int h = blockIdx.x & 7;
    const int m = idx[j];

    for (int t = tid; t < 1024; t += NTHREADS) {
        int b = t >> 6, e = t & 63;
        xs[t] = X[((size_t)((b * 8 + h) * 64 + e)) * 2048 + (size_t)(m - 1)];
    }
    const float* wrb = wr + ((size_t)(j * 8 + h)) * 4096;
    const float* wib = wi + ((size_t)(j * 8 + h)) * 4096;
    for (int t = tid; t < 4096; t += NTHREADS) { wrs[t] = wrb[t]; wis[t] = wib[t]; }
    lds_barrier();

    const int b  = tid >> 4;   // 0..15
    const int fg = tid & 15;   // 0..15
    for (int fo = 0; fo < 4; ++fo) {
        int f = fg * 4 + fo;
        float yr = 0.f, yi = 0.f;
        for (int e = 0; e < 64; ++e) {
            float2 x = xs[b * 64 + e];
            float a = wrs[e * 64 + f], c = wis[e * 64 + f];
            yr = __builtin_fmaf(x.x, a, yr); yr = __builtin_fmaf(-x.y, c, yr);
            yi = __builtin_fmaf(x.x, c, yi); yi = __builtin_fmaf( x.y, a, yi);
        }
        Y[((size_t)b * 64 + j) * 512 + (size_t)(h * 64 + f)] = make_float2(yr, yi);
    }
}

// ---------------- synthesis with full w-symmetry: 1 rotator -> 4 output rows -------------------
//   out(l)      = F0+F1+F2+F3          out(l+2048) = F0-F1+F2-F3
//   out(l+1024) = (F0-F2)-(H1-H3)      out(l+3072) = (F0-F2)+(H1-H3)
// hf-tile 32 (16 KB LDS), per-thread 2 base-l x 4 hf.
// grid: 4096 blocks = (b:16, hft:16, lt:16). Threads: r = tid>>3 (0..31), c = tid&7 (0..7).
__global__ __launch_bounds__(256, 4) void k_synth(const float2* __restrict__ Y,
                                                  const float2* __restrict__ trig,
                                                  float* __restrict__ out) {
    __shared__ __align__(16) float2 ys[64][32];  // 16 KB, pre-scaled

    const int tid = threadIdx.x;
    const int bi  = blockIdx.x;
    const int b   = bi >> 8;         // 16
    const int hft = (bi >> 4) & 15;  // 16
    const int lt  = bi & 15;         // 16

    const float invN = 1.0f / 4096.0f;
    const float2* yb = Y + (size_t)b * 64 * 512 + (size_t)hft * 32;
    for (int t = tid; t < 64 * 32; t += NTHREADS) {
        int j = t >> 5, cc = t & 31;
        float2 y = yb[(size_t)j * 512 + cc];
        if (j == 0) ys[0][cc] = make_float2(y.x * invN, 0.0f);
        else        ys[j][cc] = make_float2(y.x * (2.0f * invN), y.y * (2.0f * invN));
    }
    lds_barrier();

    const int r = tid >> 3;          // 0..31
    const int c = tid & 7;           // 0..7
    const int l0 = lt * 64 + r * 2;  // base l (v=0) in [0, 1024)

    float2 rot[2], w[2];
#pragma unroll
    for (int v = 0; v < 2; ++v) {
        w[v] = trig[(l0 + v) & 4095];
        rot[v] = make_float2(1.0f, 0.0f);
    }

    float F0[2][4], F1[2][4], F2[2][4], F3[2][4], H1[2][4], H3[2][4];
#pragma unroll
    for (int v = 0; v < 2; ++v)
#pragma unroll
        for (int u = 0; u < 4; ++u) {
            F0[v][u] = F1[v][u] = F2[v][u] = F3[v][u] = 0.0f;
            H1[v][u] = H3[v][u] = 0.0f;
        }

    // cols per thread: u=0,1 -> c*2, c*2+1 ; u=2,3 -> c*2+16, c*2+17 (two b128 loads, no conflict)
#define LOAD_YV(JROW)                                                        \
    float2 yv[4];                                                            \
    {                                                                        \
        const float4 ta = *(const float4*)&ys[(JROW)][c * 2];                \
        const float4 tb = *(const float4*)&ys[(JROW)][c * 2 + 16];           \
        yv[0] = make_float2(ta.x, ta.y); yv[1] = make_float2(ta.z, ta.w);    \
        yv[2] = make_float2(tb.x, tb.y); yv[3] = make_float2(tb.z, tb.w);    \
    }

    for (int j = 0; j < 64; j += 4) {
        // j+0 (even) -> F0
        {
            LOAD_YV(j)
#pragma unroll
            for (int v = 0; v < 2; ++v) {
                const float cx = rot[v].x, sx = rot[v].y;
#pragma unroll
                for (int u = 0; u < 4; ++u) {
                    float a = F0[v][u];
                    a = __builtin_fmaf(cx, yv[u].x, a);
                    a = __builtin_fmaf(-sx, yv[u].y, a);
                    F0[v][u] = a;
                }
                float nx = __builtin_fmaf(rot[v].x, w[v].x, -(rot[v].y * w[v].y));
                float ny = __builtin_fmaf(rot[v].x, w[v].y,  (rot[v].y * w[v].x));
                rot[v] = make_float2(nx, ny);
            }
        }
        // j+1 (odd) -> F1, H1
        {
            LOAD_YV(j + 1)
#pragma unroll
            for (int v = 0; v < 2; ++v) {
                const float cx = rot[v].x, sx = rot[v].y;
#pragma unroll
                for (int u = 0; u < 4; ++u) {
                    float a = F1[v][u], g = H1[v][u];
                    a = __builtin_fmaf(cx, yv[u].x, a);
                    a = __builtin_fmaf(-sx, yv[u].y, a);
                    g = __builtin_fmaf(sx, yv[u].x, g);
                    g = __builtin_fmaf(cx, yv[u].y, g);
                    F1[v][u] = a; H1[v][u] = g;
                }
                float nx = __builtin_fmaf(rot[v].x, w[v].x, -(rot[v].y * w[v].y));
                float ny = __builtin_fmaf(rot[v].x, w[v].y,  (rot[v].y * w[v].x));
                rot[v] = make_float2(nx, ny);
            }
        }
        // j+2 (even) -> F2
        {
            LOAD_YV(j + 2)
#pragma unroll
            for (int v = 0; v < 2; ++v) {
                const float cx = rot[v].x, sx = rot[v].y;
#pragma unroll
                for (int u = 0; u < 4; ++u) {
                    float a = F2[v][u];
                    a = __builtin_fmaf(cx, yv[u].x, a);
                    a = __builtin_fmaf(-sx, yv[u].y, a);
                    F2[v][u] = a;
                }
                float nx = __builtin_fmaf(rot[v].x, w[v].x, -(rot[v].y * w[v].y));
                float ny = __builtin_fmaf(rot[v].x, w[v].y,  (rot[v].y * w[v].x));
                rot[v] = make_float2(nx, ny);
            }
        }
        // j+3 (odd) -> F3, H3
        {
            LOAD_YV(j + 3)
#pragma unroll
            for (int v = 0; v < 2; ++v) {
                const float cx = rot[v].x, sx = rot[v].y;
#pragma unroll
                for (int u = 0; u < 4; ++u) {
                    float a = F3[v][u], g = H3[v][u];
                    a = __builtin_fmaf(cx, yv[u].x, a);
                    a = __builtin_fmaf(-sx, yv[u].y, a);
                    g = __builtin_fmaf(sx, yv[u].x, g);
                    g = __builtin_fmaf(cx, yv[u].y, g);
                    F3[v][u] = a; H3[v][u] = g;
                }
                float nx = __builtin_fmaf(rot[v].x, w[v].x, -(rot[v].y * w[v].y));
                float ny = __builtin_fmaf(rot[v].x, w[v].y,  (rot[v].y * w[v].x));
                rot[v] = make_float2(nx, ny);
            }
        }
    }
#undef LOAD_YV

    // stores: 4 rows per (v): l0+v, +1024, +2048, +3072; cols k*16 + c*2 (+1)
#pragma unroll
    for (int v = 0; v < 2; ++v) {
        float* o0 = out + ((size_t)(b * 4096 + l0 + v)) * 512 + (size_t)hft * 32;
        float* o1 = o0 + (size_t)1024 * 512;
        float* o2 = o0 + (size_t)2048 * 512;
        float* o3 = o0 + (size_t)3072 * 512;
#pragma unroll
        for (int k = 0; k < 2; ++k) {
            float2 s0, s1, s2, s3;
#pragma unroll
            for (int d = 0; d < 2; ++d) {
                const int u = 2 * k + d;
                const float p = F0[v][u] + F2[v][u];
                const float m = F0[v][u] - F2[v][u];
                const float q = F1[v][u] + F3[v][u];
                const float hh = H3[v][u] - H1[v][u];
                ((float*)&s0)[d] = p + q;
                ((float*)&s2)[d] = p - q;
                ((float*)&s1)[d] = m + hh;
                ((float*)&s3)[d] = m - hh;
            }
            *(float2*)(o0 + k * 16 + c * 2) = s0;
            *(float2*)(o1 + k * 16 + c * 2) = s1;
            *(float2*)(o2 + k * 16 + c * 2) = s2;
            *(float2*)(o3 + k * 16 + c * 2) = s3;
        }
    }
}

// ---------------- launch ----------------
extern "C" void kernel_launch(void* const* d_in, const int* in_sizes, int n_in,
                              void* d_out, int out_size, void* d_ws, size_t ws_size,
                              hipStream_t stream) {
    const float* q  = (const float*)d_in[0];
    const float* wr = (const float*)d_in[3];
    const float* wi = (const float*)d_in[4];

    char* ws = (char*)d_ws;
    float2*             trig  = (float2*)(ws + 0);                  // 32 KB
    unsigned long long* score = (unsigned long long*)(ws + 32768);  // 16 KB
    int*                idx   = (int*)(ws + 49152);                 // 256 B
    float2*             Y     = (float2*)(ws + 65536);              // 4 MB

    // d_out triples as: transposed-q scratch T -> spectrum Xout (in-place) -> final output.
    float2* Xs = (float2*)d_out;

    hipMemsetAsync(score, 0, 2048 * sizeof(unsigned long long), stream);
    k_tables<<<16, 256, 0, stream>>>(trig);
    k_xpose<<<4096, 256, 0, stream>>>(q, Xs);          // (b:16, h:8, c5:32), 128-row tiles
    k_fft<<<1024, 256, 0, stream>>>(trig, Xs, score);  // 4 planes/block, prefetch pipeline
    k_topk<<<8, 256, 0, stream>>>(score, idx);         // 2048 candidates, 1/thread
    k_proj<<<512, 256, 0, stream>>>(Xs, wr, wi, idx, Y);
    k_synth<<<4096, 256, 0, stream>>>(Y, trig, (float*)d_out);  // (b:16, hft:16, lt:16)
}

// Round 16
// 247.012 us; speedup vs baseline: 1.2545x; 1.0105x over previous
//
#include <hip/hip_runtime.h>

// Problem constants: B=16, L=4096, H=8, E=64, K=64, F=2049 (rfft bins)
// Only bins m in [1,2048] matter (bin 0 excluded from top-k; out_ft uses slots 0..63).

#define NTHREADS 256

// LDS-only barrier: drains LDS ops (lgkmcnt) but leaves global loads/stores in flight.
__device__ inline void lds_barrier() {
    asm volatile("s_waitcnt lgkmcnt(0)" ::: "memory");
    __builtin_amdgcn_s_barrier();
}

// LDS swizzle for the FFT working array: flips bits 1-3 by bits 4-6 (bijective, disjoint).
// Preserves bit 0, so (2s, 2s+1) pairs stay contiguous -> b128 pair stores are legal.
#define ZI(i) ((i) ^ ((((i) >> 4) & 7) << 1))

__device__ inline float2 f2add(float2 a, float2 b) { return make_float2(a.x + b.x, a.y + b.y); }
__device__ inline float2 f2sub(float2 a, float2 b) { return make_float2(a.x - b.x, a.y - b.y); }
// complex mul, exactly 4 VALU (mul, fma, mul, fma)
__device__ inline float2 cmulf(float2 a, float2 b) {
    return make_float2(__builtin_fmaf(a.x, b.x, -(a.y * b.y)),
                       __builtin_fmaf(a.x, b.y,  a.y * b.x));
}

// radix-16 DIT butterfly on 16 points (4 stages st..st+3 in registers).
// tA=tw[j<<(12-st)], tB=tw[j<<(11-st)], tC=tw[j<<(10-st)], tD=tw[j<<(9-st)].
// Layer twiddle composition: stage st+1 adds factor (-i)^(k&1) [W^1024], st+2 adds
// w8^(k&3) [W^512 = e^{-i pi/4}], st+3 adds w16^(k&7) [W^256 = e^{-i pi/8}].
__device__ inline void radix16(float2 x[16], float2 tA, float2 tB, float2 tC, float2 tD) {
    // L1: pairs (2q, 2q+1), twiddle tA
#pragma unroll
    for (int q = 0; q < 8; ++q) {
        float2 v = cmulf(tA, x[2 * q + 1]);
        float2 u = x[2 * q];
        x[2 * q]     = f2add(u, v);
        x[2 * q + 1] = f2sub(u, v);
    }
    // L2: pairs (4q+r, 4q+r+2); r=0 -> tB, r=1 -> -i*tB (free swap)
    {
        float2 tB1 = make_float2(tB.y, -tB.x);
#pragma unroll
        for (int q = 0; q < 4; ++q) {
            {
                float2 v = cmulf(tB, x[4 * q + 2]);
                float2 u = x[4 * q];
                x[4 * q]     = f2add(u, v);
                x[4 * q + 2] = f2sub(u, v);
            }
            {
                float2 v = cmulf(tB1, x[4 * q + 3]);
                float2 u = x[4 * q + 1];
                x[4 * q + 1] = f2add(u, v);
                x[4 * q + 3] = f2sub(u, v);
            }
        }
    }
    // L3: pairs (8q+r, 8q+r+4), w = tC * w8^r
    {
        const float C = 0.70710678118654752f;
        float2 w0 = tC;
        float2 w1 = cmulf(tC, make_float2(C, -C));
        float2 w2 = make_float2(tC.y, -tC.x);
        float2 w3 = cmulf(tC, make_float2(-C, -C));
#pragma unroll
        for (int q = 0; q < 2; ++q) {
            float2 ws[4] = {w0, w1, w2, w3};
#pragma unroll
            for (int r = 0; r < 4; ++r) {
                float2 v = cmulf(ws[r], x[8 * q + r + 4]);
                float2 u = x[8 * q + r];
                x[8 * q + r]     = f2add(u, v);
                x[8 * q + r + 4] = f2sub(u, v);
            }
        }
    }
    // L4: pairs (r, r+8), w = tD * w16^r, w16^r = (cos(r pi/8), -sin(r pi/8))
    {
        const float C  = 0.70710678118654752f;
        const float C1 = 0.92387953251128676f;  // cos(pi/8)
        const float S1 = 0.38268343236508977f;  // sin(pi/8)
        float2 wD[8];
        wD[0] = tD;
        wD[1] = cmulf(tD, make_float2(C1, -S1));
        wD[2] = cmulf(tD, make_float2(C, -C));
        wD[3] = cmulf(tD, make_float2(S1, -C1));
        wD[4] = make_float2(tD.y, -tD.x);
        wD[5] = cmulf(tD, make_float2(-S1, -C1));
        wD[6] = cmulf(tD, make_float2(-C, -C));
        wD[7] = cmulf(tD, make_float2(-C1, -S1));
#pragma unroll
        for (int r = 0; r < 8; ++r) {
            float2 v = cmulf(wD[r], x[r + 8]);
            float2 u = x[r];
            x[r]     = f2add(u, v);
            x[r + 8] = f2sub(u, v);
        }
    }
}

// ---------------- table kernel: trig[k] = (cos, sin)(2*pi*k/4096), f64-accurate ----------------
__global__ void k_tables(float2* __restrict__ trig) {
    int k = blockIdx.x * blockDim.x + threadIdx.x;
    if (k < 4096) {
        double th = (6.283185307179586476925286766559 * (double)k) / 4096.0;
        trig[k] = make_float2((float)cos(th), (float)sin(th));
    }
}

// ---------------- transpose + bit-reversal: q[b,l,h,e] -> T[(b,h,eo)][p][j] (float2) -----------
// 128-row tiles (33 KB LDS -> 4 blocks/CU). Block (b:16, h:8, c5:32).
__global__ __launch_bounds__(256) void k_xpose(const float* __restrict__ q,
                                               float2* __restrict__ T) {
    __shared__ float tile[128][65];  // 33 KB, padded (+1)

    const int tid = threadIdx.x;
    const int bi  = blockIdx.x;
    const int b   = bi >> 8;
    const int h   = (bi >> 5) & 7;
    const int c5  = bi & 31;

    const float* qb = q + ((size_t)b * 4096 * 512) + (size_t)h * 64;
#pragma unroll
    for (int i = 0; i < 8; ++i) {
        const int f = tid + 256 * i;
        const int t = f >> 4, e4 = f & 15;
        const float4 v = *(const float4*)(qb + (size_t)(c5 + 32 * t) * 512 + e4 * 4);
        tile[t][e4 * 4 + 0] = v.x;
        tile[t][e4 * 4 + 1] = v.y;
        tile[t][e4 * 4 + 2] = v.z;
        tile[t][e4 * 4 + 3] = v.w;
    }
    lds_barrier();

    const int wave = tid >> 6, lane = tid & 63;
    const int rl  = __brev(lane) >> 26;  // rev6(lane)
    const int r5c = __brev(c5) >> 27;    // rev5(c5)
    for (int cc = wave; cc < 32; cc += 4) {
        const int eo = cc >> 2, p = cc & 3;
        const int col0 = eo * 8 + 2 * p;
        float2* dst = T + ((size_t)((b * 8 + h) * 8 + eo)) * 16384 + (size_t)p * 4096
                        + (size_t)r5c * 128;
        float4 o;
        o.x = tile[rl][col0];      o.y = tile[rl][col0 + 1];
        o.z = tile[rl + 64][col0]; o.w = tile[rl + 64][col0 + 1];
        *(float4*)(dst + 2 * lane) = o;  // 16B/lane, contiguous 1KB run per (eo,p)
    }
}

// ---------------- FFT (3 x radix-16 passes) + spectrum store + score accumulation --------------
// 1024 blocks, 4-plane register-prefetch pipeline, eacc in registers.
// 12 stages = pass0 (st=1..4, registers, constant twiddles) + pass1 (st=5, h=16, LDS) +
// pass2 (st=9, h=256, LDS, twiddles from global trig). One butterfly per thread per pass.
__global__ __launch_bounds__(256) void k_fft(const float2* __restrict__ trig,
                                             float2* __restrict__ Xout,
                                             unsigned long long* __restrict__ score) {
    __shared__ float2 z[4096];    // 32 KB (swizzled indexing)
    __shared__ float2 ctw4[80];   // pass1 quads, stride-5 layout (conflict-free mod 16)

    const int tid = threadIdx.x;
    const int bi  = blockIdx.x;

    // pass1 twiddle quads: ctw4[5j+qq] = conj(trig[j << (7-qq)]), j<16, qq<4
    if (tid < 64) {
        const int j = tid >> 2, qq = tid & 3;
        float2 a = trig[j << (7 - qq)];
        ctw4[5 * j + qq] = make_float2(a.x, -a.y);
    }

    float eaccr[8];
#pragma unroll
    for (int k = 0; k < 8; ++k) eaccr[k] = 0.f;

    const float2 ONE = make_float2(1.0f, 0.0f);
    const float2* base = Xout + (size_t)bi * 16384;

    // prefetch plane 0: thread t owns 16 contiguous float2 at 16t (8 float4)
    float4 pre[8];
#pragma unroll
    for (int g = 0; g < 8; ++g) pre[g] = *(const float4*)(base + 16 * tid + 2 * g);
    lds_barrier();  // ctw4 ready (prefetch loads stay in flight)

    for (int p = 0; p < 4; ++p) {
        // consume prefetch into x, then immediately issue next plane's loads
        float2 x[16];
#pragma unroll
        for (int g = 0; g < 8; ++g) {
            x[2 * g]     = make_float2(pre[g].x, pre[g].y);
            x[2 * g + 1] = make_float2(pre[g].z, pre[g].w);
        }
        if (p < 3) {
            const float2* pn = base + (size_t)(p + 1) * 4096;
#pragma unroll
            for (int g = 0; g < 8; ++g) pre[g] = *(const float4*)(pn + 16 * tid + 2 * g);
        }

        // pass 0: stages 1-4 on 16 contiguous bit-reversed points, constant twiddles
        radix16(x, ONE, ONE, ONE, ONE);
        {
            const int i0 = 16 * tid;
#pragma unroll
            for (int s = 0; s < 8; ++s) {
                // ZI keeps (2s,2s+1) contiguous -> b128 pair store
                *(float4*)&z[ZI(i0 + 2 * s)] = make_float4(x[2 * s].x, x[2 * s].y,
                                                           x[2 * s + 1].x, x[2 * s + 1].y);
            }
        }
        lds_barrier();

        // pass 1: st=5, h=16. j = tid&15, g = tid>>4, i0 = (g<<8)+j.
        {
            const int j = tid & 15;
            const int g = tid >> 4;
            const int i0 = (g << 8) + j;
            int ad[16];
#pragma unroll
            for (int k = 0; k < 16; ++k) ad[k] = ZI(i0 + 16 * k);
#pragma unroll
            for (int k = 0; k < 16; ++k) x[k] = z[ad[k]];
            const float2 tA = ctw4[5 * j + 0];
            const float2 tB = ctw4[5 * j + 1];
            const float2 tC = ctw4[5 * j + 2];
            const float2 tD = ctw4[5 * j + 3];
            radix16(x, tA, tB, tC, tD);
#pragma unroll
            for (int k = 0; k < 16; ++k) z[ad[k]] = x[k];
        }
        lds_barrier();

        // pass 2: st=9, h=256. j = tid, i0 = j; twiddles from global trig (L1-hot)
        {
            const int j = tid;
            int ad[16];
#pragma unroll
            for (int k = 0; k < 16; ++k) ad[k] = ZI(j + 256 * k);
#pragma unroll
            for (int k = 0; k < 16; ++k) x[k] = z[ad[k]];
            float2 a = trig[j << 3], b2 = trig[j << 2], c = trig[j << 1], d = trig[j];
            const float2 tA = make_float2(a.x, -a.y);
            const float2 tB = make_float2(b2.x, -b2.y);
            const float2 tC = make_float2(c.x, -c.y);
            const float2 tD = make_float2(d.x, -d.y);
            radix16(x, tA, tB, tC, tD);
#pragma unroll
            for (int k = 0; k < 16; ++k) z[ad[k]] = x[k];
        }
        lds_barrier();

        // unpack two real spectra; store (overwrites this pair's own plane); accumulate energy
        {
            const size_t s0 = (size_t)bi * 16384 + (size_t)p * 4096;  // = signal (bi*8+2p) * 2048
#pragma unroll
            for (int k = 0; k < 8; ++k) {
                const int t = tid + 256 * k;
                const int m = t + 1;
                float2 Za = z[ZI(m)];
                float2 Zb = z[ZI(4096 - m)];
                float Xr0 = 0.5f * (Za.x + Zb.x);
                float Xi0 = 0.5f * (Za.y - Zb.y);
                float Xr1 = 0.5f * (Za.y + Zb.y);
                float Xi1 = 0.5f * (Zb.x - Za.x);
                Xout[s0 + t]        = make_float2(Xr0, Xi0);
                Xout[s0 + 2048 + t] = make_float2(Xr1, Xi1);
                eaccr[k] += Xr0 * Xr0 + Xi0 * Xi0 + Xr1 * Xr1 + Xi1 * Xi1;
            }
        }
        lds_barrier();  // z reads done; stores drain lazily under next plane's compute
    }

    // deterministic reduction: fixed-point u64 atomics (integer adds commute exactly)
#pragma unroll
    for (int k = 0; k < 8; ++k) {
        unsigned long long v = (unsigned long long)llrintf(eaccr[k] * 1048576.0f);  // 2^20
        atomicAdd(&score[tid + 256 * k], v);
    }
}

// ---------------- top-64, parallelized: 8 blocks x 256 threads, one candidate per thread -------
__global__ __launch_bounds__(256) void k_topk(const unsigned long long* __restrict__ score,
                                              int* __restrict__ idx) {
    __shared__ unsigned long long s[2048];
    const int tid = threadIdx.x;
    for (int t = tid; t < 2048; t += 256) s[t] = score[t];
    __syncthreads();

    const int t = blockIdx.x * 256 + tid;  // 0..2047
    const unsigned long long my = s[t];
    int rank = 0;
#pragma unroll 8
    for (int u = 0; u < 2048; ++u) {
        unsigned long long o = s[u];
        rank += (int)((o > my) || (o == my && u < t));
    }
    if (rank < 64) idx[rank] = t + 1;  // store frequency index m
}

// ---------------- gather + complex projection: Y[b,j,h,f] = sum_e X[b,idx_j,h,e] * W[j,h,e,f] ----
__global__ __launch_bounds__(256) void k_proj(const float2* __restrict__ X,
                                              const float* __restrict__ wr,
                                              const float* __restrict__ wi,
                                              const int* __restrict__ idx,
                                              float2* __restrict__ Y) {
    __shared__ float2 xs[16 * 64];   // [b][e]  8 KB
    __shared__ float  wrs[64 * 64];  // [e][f] 16 KB
    __shared__ float  wis[64 * 64];  // 16 KB

    const int tid = threadIdx.x;
    const int j = blockIdx.x >> 3;
    const int h = blockIdx.x & 7;
    const int m = idx[j];

    for (int t = tid; t < 1024; t += NTHREADS) {
        int b = t >> 6, e = t & 63;
        xs[t] = X[((size_t)((b * 8 + h) * 64 + e)) * 2048 + (size_t)(m - 1)];
    }
    const float* wrb = wr + ((size_t)(j * 8 + h)) * 4096;
    const float* wib = wi + ((size_t)(j * 8 + h)) * 4096;
    for (int t = tid; t < 4096; t += NTHREADS) { wrs[t] = wrb[t]; wis[t] = wib[t]; }
    lds_barrier();

    const int b  = tid >> 4;   // 0..15
    const int fg = tid & 15;   // 0..15
    for (int fo = 0; fo < 4; ++fo) {
        int f = fg * 4 + fo;
        float yr = 0.f, yi = 0.f;
        for (int e = 0; e < 64; ++e) {
            float2 x = xs[b * 64 + e];
            float a = wrs[e * 64 + f], c = wis[e * 64 + f];
            yr = __builtin_fmaf(x.x, a, yr); yr = __builtin_fmaf(-x.y, c, yr);
            yi = __builtin_fmaf(x.x, c, yi); yi = __builtin_fmaf( x.y, a, yi);
        }
        Y[((size_t)b * 64 + j) * 512 + (size_t)(h * 64 + f)] = make_float2(yr, yi);
    }
}

// ---------------- synthesis with full w-symmetry: 1 rotator -> 4 output rows -------------------
//   out(l)      = F0+F1+F2+F3          out(l+2048) = F0-F1+F2-F3
//   out(l+1024) = (F0-F2)-(H1-H3)      out(l+3072) = (F0-F2)+(H1-H3)
// hf-tile 32 (16 KB LDS), per-thread 2 base-l x 4 hf.
// grid: 4096 blocks = (b:16, hft:16, lt:16). Threads: r = tid>>3 (0..31), c = tid&7 (0..7).
__global__ __launch_bounds__(256, 4) void k_synth(const float2* __restrict__ Y,
                                                  const float2* __restrict__ trig,
                                                  float* __restrict__ out) {
    __shared__ __align__(16) float2 ys[64][32];  // 16 KB, pre-scaled

    const int tid = threadIdx.x;
    const int bi  = blockIdx.x;
    const int b   = bi >> 8;         // 16
    const int hft = (bi >> 4) & 15;  // 16
    const int lt  = bi & 15;         // 16

    const float invN = 1.0f / 4096.0f;
    const float2* yb = Y + (size_t)b * 64 * 512 + (size_t)hft * 32;
    for (int t = tid; t < 64 * 32; t += NTHREADS) {
        int j = t >> 5, cc = t & 31;
        float2 y = yb[(size_t)j * 512 + cc];
        if (j == 0) ys[0][cc] = make_float2(y.x * invN, 0.0f);
        else        ys[j][cc] = make_float2(y.x * (2.0f * invN), y.y * (2.0f * invN));
    }
    lds_barrier();

    const int r = tid >> 3;          // 0..31
    const int c = tid & 7;           // 0..7
    const int l0 = lt * 64 + r * 2;  // base l (v=0) in [0, 1024)

    float2 rot[2], w[2];
#pragma unroll
    for (int v = 0; v < 2; ++v) {
        w[v] = trig[(l0 + v) & 4095];
        rot[v] = make_float2(1.0f, 0.0f);
    }

    float F0[2][4], F1[2][4], F2[2][4], F3[2][4], H1[2][4], H3[2][4];
#pragma unroll
    for (int v = 0; v < 2; ++v)
#pragma unroll
        for (int u = 0; u < 4; ++u) {
            F0[v][u] = F1[v][u] = F2[v][u] = F3[v][u] = 0.0f;
            H1[v][u] = H3[v][u] = 0.0f;
        }

#define LOAD_YV(JROW)                                                        \
    float2 yv[4];                                                            \
    {                                                                        \
        const float4 ta = *(const float4*)&ys[(JROW)][c * 2];                \
        const float4 tb = *(const float4*)&ys[(JROW)][c * 2 + 16];           \
        yv[0] = make_float2(ta.x, ta.y); yv[1] = make_float2(ta.z, ta.w);    \
        yv[2] = make_float2(tb.x, tb.y); yv[3] = make_float2(tb.z, tb.w);    \
    }

    for (int j = 0; j < 64; j += 4) {
        {
            LOAD_YV(j)
#pragma unroll
            for (int v = 0; v < 2; ++v) {
                const float cx = rot[v].x, sx = rot[v].y;
#pragma unroll
                for (int u = 0; u < 4; ++u) {
                    float a = F0[v][u];
                    a = __builtin_fmaf(cx, yv[u].x, a);
                    a = __builtin_fmaf(-sx, yv[u].y, a);
                    F0[v][u] = a;
                }
                float nx = __builtin_fmaf(rot[v].x, w[v].x, -(rot[v].y * w[v].y));
                float ny = __builtin_fmaf(rot[v].x, w[v].y,  (rot[v].y * w[v].x));
                rot[v] = make_float2(nx, ny);
            }
        }
        {
            LOAD_YV(j + 1)
#pragma unroll
            for (int v = 0; v < 2; ++v) {
                const float cx = rot[v].x, sx = rot[v].y;
#pragma unroll
                for (int u = 0; u < 4; ++u) {
                    float a = F1[v][u], g = H1[v][u];
                    a = __builtin_fmaf(cx, yv[u].x, a);
                    a = __builtin_fmaf(-sx, yv[u].y, a);
                    g = __builtin_fmaf(sx, yv[u].x, g);
                    g = __builtin_fmaf(cx, yv[u].y, g);
                    F1[v][u] = a; H1[v][u] = g;
                }
                float nx = __builtin_fmaf(rot[v].x, w[v].x, -(rot[v].y * w[v].y));
                float ny = __builtin_fmaf(rot[v].x, w[v].y,  (rot[v].y * w[v].x));
                rot[v] = make_float2(nx, ny);
            }
        }
        {
            LOAD_YV(j + 2)
#pragma unroll
            for (int v = 0; v < 2; ++v) {
                const float cx = rot[v].x, sx = rot[v].y;
#pragma unroll
                for (int u = 0; u < 4; ++u) {
                    float a = F2[v][u];
                    a = __builtin_fmaf(cx, yv[u].x, a);
                    a = __builtin_fmaf(-sx, yv[u].y, a);
                    F2[v][u] = a;
                }
                float nx = __builtin_fmaf(rot[v].x, w[v].x, -(rot[v].y * w[v].y));
                float ny = __builtin_fmaf(rot[v].x, w[v].y,  (rot[v].y * w[v].x));
                rot[v] = make_float2(nx, ny);
            }
        }
        {
            LOAD_YV(j + 3)
#pragma unroll
            for (int v = 0; v < 2; ++v) {
                const float cx = rot[v].x, sx = rot[v].y;
#pragma unroll
                for (int u = 0; u < 4; ++u) {
                    float a = F3[v][u], g = H3[v][u];
                    a = __builtin_fmaf(cx, yv[u].x, a);
                    a = __builtin_fmaf(-sx, yv[u].y, a);
                    g = __builtin_fmaf(sx, yv[u].x, g);
                    g = __builtin_fmaf(cx, yv[u].y, g);
                    F3[v][u] = a; H3[v][u] = g;
                }
                float nx = __builtin_fmaf(rot[v].x, w[v].x, -(rot[v].y * w[v].y));
                float ny = __builtin_fmaf(rot[v].x, w[v].y,  (rot[v].y * w[v].x));
                rot[v] = make_float2(nx, ny);
            }
        }
    }
#undef LOAD_YV

#pragma unroll
    for (int v = 0; v < 2; ++v) {
        float* o0 = out + ((size_t)(b * 4096 + l0 + v)) * 512 + (size_t)hft * 32;
        float* o1 = o0 + (size_t)1024 * 512;
        float* o2 = o0 + (size_t)2048 * 512;
        float* o3 = o0 + (size_t)3072 * 512;
#pragma unroll
        for (int k = 0; k < 2; ++k) {
            float2 s0, s1, s2, s3;
#pragma unroll
            for (int d = 0; d < 2; ++d) {
                const int u = 2 * k + d;
                const float p = F0[v][u] + F2[v][u];
                const float m = F0[v][u] - F2[v][u];
                const float q = F1[v][u] + F3[v][u];
                const float hh = H3[v][u] - H1[v][u];
                ((float*)&s0)[d] = p + q;
                ((float*)&s2)[d] = p - q;
                ((float*)&s1)[d] = m + hh;
                ((float*)&s3)[d] = m - hh;
            }
            *(float2*)(o0 + k * 16 + c * 2) = s0;
            *(float2*)(o1 + k * 16 + c * 2) = s1;
            *(float2*)(o2 + k * 16 + c * 2) = s2;
            *(float2*)(o3 + k * 16 + c * 2) = s3;
        }
    }
}

// ---------------- launch ----------------
extern "C" void kernel_launch(void* const* d_in, const int* in_sizes, int n_in,
                              void* d_out, int out_size, void* d_ws, size_t ws_size,
                              hipStream_t stream) {
    const float* q  = (const float*)d_in[0];
    const float* wr = (const float*)d_in[3];
    const float* wi = (const float*)d_in[4];

    char* ws = (char*)d_ws;
    float2*             trig  = (float2*)(ws + 0);                  // 32 KB
    unsigned long long* score = (unsigned long long*)(ws + 32768);  // 16 KB
    int*                idx   = (int*)(ws + 49152);                 // 256 B
    float2*             Y     = (float2*)(ws + 65536);              // 4 MB

    // d_out triples as: transposed-q scratch T -> spectrum Xout (in-place) -> final output.
    float2* Xs = (float2*)d_out;

    hipMemsetAsync(score, 0, 2048 * sizeof(unsigned long long), stream);
    k_tables<<<16, 256, 0, stream>>>(trig);
    k_xpose<<<4096, 256, 0, stream>>>(q, Xs);          // (b:16, h:8, c5:32), 128-row tiles
    k_fft<<<1024, 256, 0, stream>>>(trig, Xs, score);  // radix-16 x3, 4 planes/block
    k_topk<<<8, 256, 0, stream>>>(score, idx);         // 2048 candidates, 1/thread
    k_proj<<<512, 256, 0, stream>>>(Xs, wr, wi, idx, Y);
    k_synth<<<4096, 256, 0, stream>>>(Y, trig, (float*)d_out);  // (b:16, hft:16, lt:16)
}

// Round 17
// 241.897 us; speedup vs baseline: 1.2811x; 1.0211x over previous
//
#include <hip/hip_runtime.h>

// Problem constants: B=16, L=4096, H=8, E=64, K=64, F=2049 (rfft bins)
// Only bins m in [1,2048] matter (bin 0 excluded from top-k; out_ft uses slots 0..63).

#define NTHREADS 256

// LDS-only barrier: drains LDS ops (lgkmcnt) but leaves global loads/stores in flight.
__device__ inline void lds_barrier() {
    asm volatile("s_waitcnt lgkmcnt(0)" ::: "memory");
    __builtin_amdgcn_s_barrier();
}

// LDS swizzle for the FFT working array: flips bits 1-3 by bits 4-6 (bijective, disjoint).
// Preserves bit 0, so (2s, 2s+1) pairs stay contiguous -> b128 pair stores are legal.
#define ZI(i) ((i) ^ ((((i) >> 4) & 7) << 1))

__device__ inline float2 f2add(float2 a, float2 b) { return make_float2(a.x + b.x, a.y + b.y); }
__device__ inline float2 f2sub(float2 a, float2 b) { return make_float2(a.x - b.x, a.y - b.y); }
// complex mul, exactly 4 VALU (mul, fma, mul, fma)
__device__ inline float2 cmulf(float2 a, float2 b) {
    return make_float2(__builtin_fmaf(a.x, b.x, -(a.y * b.y)),
                       __builtin_fmaf(a.x, b.y,  a.y * b.x));
}

// radix-16 DIT butterfly on 16 points (4 stages st..st+3 in registers).
__device__ inline void radix16(float2 x[16], float2 tA, float2 tB, float2 tC, float2 tD) {
    // L1: pairs (2q, 2q+1), twiddle tA
#pragma unroll
    for (int q = 0; q < 8; ++q) {
        float2 v = cmulf(tA, x[2 * q + 1]);
        float2 u = x[2 * q];
        x[2 * q]     = f2add(u, v);
        x[2 * q + 1] = f2sub(u, v);
    }
    // L2: pairs (4q+r, 4q+r+2); r=0 -> tB, r=1 -> -i*tB (free swap)
    {
        float2 tB1 = make_float2(tB.y, -tB.x);
#pragma unroll
        for (int q = 0; q < 4; ++q) {
            {
                float2 v = cmulf(tB, x[4 * q + 2]);
                float2 u = x[4 * q];
                x[4 * q]     = f2add(u, v);
                x[4 * q + 2] = f2sub(u, v);
            }
            {
                float2 v = cmulf(tB1, x[4 * q + 3]);
                float2 u = x[4 * q + 1];
                x[4 * q + 1] = f2add(u, v);
                x[4 * q + 3] = f2sub(u, v);
            }
        }
    }
    // L3: pairs (8q+r, 8q+r+4), w = tC * w8^r
    {
        const float C = 0.70710678118654752f;
        float2 w0 = tC;
        float2 w1 = cmulf(tC, make_float2(C, -C));
        float2 w2 = make_float2(tC.y, -tC.x);
        float2 w3 = cmulf(tC, make_float2(-C, -C));
#pragma unroll
        for (int q = 0; q < 2; ++q) {
            float2 ws[4] = {w0, w1, w2, w3};
#pragma unroll
            for (int r = 0; r < 4; ++r) {
                float2 v = cmulf(ws[r], x[8 * q + r + 4]);
                float2 u = x[8 * q + r];
                x[8 * q + r]     = f2add(u, v);
                x[8 * q + r + 4] = f2sub(u, v);
            }
        }
    }
    // L4: pairs (r, r+8), w = tD * w16^r
    {
        const float C  = 0.70710678118654752f;
        const float C1 = 0.92387953251128676f;  // cos(pi/8)
        const float S1 = 0.38268343236508977f;  // sin(pi/8)
        float2 wD[8];
        wD[0] = tD;
        wD[1] = cmulf(tD, make_float2(C1, -S1));
        wD[2] = cmulf(tD, make_float2(C, -C));
        wD[3] = cmulf(tD, make_float2(S1, -C1));
        wD[4] = make_float2(tD.y, -tD.x);
        wD[5] = cmulf(tD, make_float2(-S1, -C1));
        wD[6] = cmulf(tD, make_float2(-C, -C));
        wD[7] = cmulf(tD, make_float2(-C1, -S1));
#pragma unroll
        for (int r = 0; r < 8; ++r) {
            float2 v = cmulf(wD[r], x[r + 8]);
            float2 u = x[r];
            x[r]     = f2add(u, v);
            x[r + 8] = f2sub(u, v);
        }
    }
}

// ---------------- tables + score zeroing ------------------------------------------------------
__global__ void k_tables(float2* __restrict__ trig, unsigned long long* __restrict__ score) {
    int k = blockIdx.x * blockDim.x + threadIdx.x;
    if (k < 4096) {
        double th = (6.283185307179586476925286766559 * (double)k) / 4096.0;
        trig[k] = make_float2((float)cos(th), (float)sin(th));
    }
    if (k < 2048) score[k] = 0ULL;
}

// ---------------- transpose + bit-reversal: q[b,l,h,e] -> T[(b,h,eo)][p][j] (float2) -----------
// 128-row tiles (33 KB LDS -> 4 blocks/CU). Block (b:16, h:8, c5:32).
__global__ __launch_bounds__(256) void k_xpose(const float* __restrict__ q,
                                               float2* __restrict__ T) {
    __shared__ float tile[128][65];  // 33 KB, padded (+1)

    const int tid = threadIdx.x;
    const int bi  = blockIdx.x;
    const int b   = bi >> 8;
    const int h   = (bi >> 5) & 7;
    const int c5  = bi & 31;

    const float* qb = q + ((size_t)b * 4096 * 512) + (size_t)h * 64;
#pragma unroll
    for (int i = 0; i < 8; ++i) {
        const int f = tid + 256 * i;
        const int t = f >> 4, e4 = f & 15;
        const float4 v = *(const float4*)(qb + (size_t)(c5 + 32 * t) * 512 + e4 * 4);
        tile[t][e4 * 4 + 0] = v.x;
        tile[t][e4 * 4 + 1] = v.y;
        tile[t][e4 * 4 + 2] = v.z;
        tile[t][e4 * 4 + 3] = v.w;
    }
    lds_barrier();

    const int wave = tid >> 6, lane = tid & 63;
    const int rl  = __brev(lane) >> 26;  // rev6(lane)
    const int r5c = __brev(c5) >> 27;    // rev5(c5)
    for (int cc = wave; cc < 32; cc += 4) {
        const int eo = cc >> 2, p = cc & 3;
        const int col0 = eo * 8 + 2 * p;
        float2* dst = T + ((size_t)((b * 8 + h) * 8 + eo)) * 16384 + (size_t)p * 4096
                        + (size_t)r5c * 128;
        float4 o;
        o.x = tile[rl][col0];      o.y = tile[rl][col0 + 1];
        o.z = tile[rl + 64][col0]; o.w = tile[rl + 64][col0 + 1];
        *(float4*)(dst + 2 * lane) = o;  // 16B/lane, contiguous 1KB run per (eo,p)
    }
}

// ---------------- FFT (3 x radix-16 passes) + spectrum store + score accumulation --------------
__global__ __launch_bounds__(256) void k_fft(const float2* __restrict__ trig,
                                             float2* __restrict__ Xout,
                                             unsigned long long* __restrict__ score) {
    __shared__ float2 z[4096];    // 32 KB (swizzled indexing)
    __shared__ float2 ctw4[80];   // pass1 quads, stride-5 layout (conflict-free mod 16)

    const int tid = threadIdx.x;
    const int bi  = blockIdx.x;

    // pass1 twiddle quads: ctw4[5j+qq] = conj(trig[j << (7-qq)]), j<16, qq<4
    if (tid < 64) {
        const int j = tid >> 2, qq = tid & 3;
        float2 a = trig[j << (7 - qq)];
        ctw4[5 * j + qq] = make_float2(a.x, -a.y);
    }

    float eaccr[8];
#pragma unroll
    for (int k = 0; k < 8; ++k) eaccr[k] = 0.f;

    const float2 ONE = make_float2(1.0f, 0.0f);
    const float2* base = Xout + (size_t)bi * 16384;

    // prefetch plane 0: thread t owns 16 contiguous float2 at 16t (8 float4)
    float4 pre[8];
#pragma unroll
    for (int g = 0; g < 8; ++g) pre[g] = *(const float4*)(base + 16 * tid + 2 * g);
    lds_barrier();  // ctw4 ready (prefetch loads stay in flight)

    for (int p = 0; p < 4; ++p) {
        float2 x[16];
#pragma unroll
        for (int g = 0; g < 8; ++g) {
            x[2 * g]     = make_float2(pre[g].x, pre[g].y);
            x[2 * g + 1] = make_float2(pre[g].z, pre[g].w);
        }
        if (p < 3) {
            const float2* pn = base + (size_t)(p + 1) * 4096;
#pragma unroll
            for (int g = 0; g < 8; ++g) pre[g] = *(const float4*)(pn + 16 * tid + 2 * g);
        }

        // pass 0: stages 1-4 on 16 contiguous bit-reversed points, constant twiddles
        radix16(x, ONE, ONE, ONE, ONE);
        {
            const int i0 = 16 * tid;
#pragma unroll
            for (int s = 0; s < 8; ++s) {
                *(float4*)&z[ZI(i0 + 2 * s)] = make_float4(x[2 * s].x, x[2 * s].y,
                                                           x[2 * s + 1].x, x[2 * s + 1].y);
            }
        }
        lds_barrier();

        // pass 1: st=5, h=16. j = tid&15, g = tid>>4, i0 = (g<<8)+j.
        {
            const int j = tid & 15;
            const int g = tid >> 4;
            const int i0 = (g << 8) + j;
            int ad[16];
#pragma unroll
            for (int k = 0; k < 16; ++k) ad[k] = ZI(i0 + 16 * k);
#pragma unroll
            for (int k = 0; k < 16; ++k) x[k] = z[ad[k]];
            const float2 tA = ctw4[5 * j + 0];
            const float2 tB = ctw4[5 * j + 1];
            const float2 tC = ctw4[5 * j + 2];
            const float2 tD = ctw4[5 * j + 3];
            radix16(x, tA, tB, tC, tD);
#pragma unroll
            for (int k = 0; k < 16; ++k) z[ad[k]] = x[k];
        }
        lds_barrier();

        // pass 2: st=9, h=256. j = tid; twiddles from global trig (L1-hot)
        {
            const int j = tid;
            int ad[16];
#pragma unroll
            for (int k = 0; k < 16; ++k) ad[k] = ZI(j + 256 * k);
#pragma unroll
            for (int k = 0; k < 16; ++k) x[k] = z[ad[k]];
            float2 a = trig[j << 3], b2 = trig[j << 2], c = trig[j << 1], d = trig[j];
            const float2 tA = make_float2(a.x, -a.y);
            const float2 tB = make_float2(b2.x, -b2.y);
            const float2 tC = make_float2(c.x, -c.y);
            const float2 tD = make_float2(d.x, -d.y);
            radix16(x, tA, tB, tC, tD);
#pragma unroll
            for (int k = 0; k < 16; ++k) z[ad[k]] = x[k];
        }
        lds_barrier();

        // unpack two real spectra; store (overwrites this pair's own plane); accumulate energy
        {
            const size_t s0 = (size_t)bi * 16384 + (size_t)p * 4096;  // = signal (bi*8+2p) * 2048
#pragma unroll
            for (int k = 0; k < 8; ++k) {
                const int t = tid + 256 * k;
                const int m = t + 1;
                float2 Za = z[ZI(m)];
                float2 Zb = z[ZI(4096 - m)];
                float Xr0 = 0.5f * (Za.x + Zb.x);
                float Xi0 = 0.5f * (Za.y - Zb.y);
                float Xr1 = 0.5f * (Za.y + Zb.y);
                float Xi1 = 0.5f * (Zb.x - Za.x);
                Xout[s0 + t]        = make_float2(Xr0, Xi0);
                Xout[s0 + 2048 + t] = make_float2(Xr1, Xi1);
                eaccr[k] += Xr0 * Xr0 + Xi0 * Xi0 + Xr1 * Xr1 + Xi1 * Xi1;
            }
        }
        lds_barrier();  // z reads done; stores drain lazily under next plane's compute
    }

    // deterministic reduction: fixed-point u64 atomics (integer adds commute exactly)
#pragma unroll
    for (int k = 0; k < 8; ++k) {
        unsigned long long v = (unsigned long long)llrintf(eaccr[k] * 1048576.0f);  // 2^20
        atomicAdd(&score[tid + 256 * k], v);
    }
}

// ---------------- top-64, parallelized: 8 blocks x 256 threads, one candidate per thread -------
__global__ __launch_bounds__(256) void k_topk(const unsigned long long* __restrict__ score,
                                              int* __restrict__ idx) {
    __shared__ unsigned long long s[2048];
    const int tid = threadIdx.x;
    for (int t = tid; t < 2048; t += 256) s[t] = score[t];
    __syncthreads();

    const int t = blockIdx.x * 256 + tid;  // 0..2047
    const unsigned long long my = s[t];
    int rank = 0;
#pragma unroll 8
    for (int u = 0; u < 2048; ++u) {
        unsigned long long o = s[u];
        rank += (int)((o > my) || (o == my && u < t));
    }
    if (rank < 64) idx[rank] = t + 1;  // store frequency index m
}

// ---------------- gather + complex projection: Y[b,j,h,f] = sum_e X[b,idx_j,h,e] * W[j,h,e,f] ----
// 2048 blocks = (j:64, h:8, bq:4). Per block: 4 b-values x 64 f. One gather load and one
// output per thread; e-loop unrolled x4 with broadcast float4 xs reads + conflict-free W reads.
__global__ __launch_bounds__(256) void k_proj(const float2* __restrict__ X,
                                              const float* __restrict__ wr,
                                              const float* __restrict__ wi,
                                              const int* __restrict__ idx,
                                              float2* __restrict__ Y) {
    __shared__ __align__(16) float2 xs[4 * 64];  // [b_loc][e]  2 KB
    __shared__ float  wrs[64 * 64];              // [e][f] 16 KB
    __shared__ float  wis[64 * 64];              // 16 KB

    const int tid = threadIdx.x;
    const int j  = blockIdx.x >> 5;
    const int h  = (blockIdx.x >> 2) & 7;
    const int bq = blockIdx.x & 3;
    const int m = idx[j];

    // gather: one load per thread
    {
        const int bl = tid >> 6, e = tid & 63;
        xs[tid] = X[((size_t)(((bq * 4 + bl) * 8 + h) * 64 + e)) * 2048 + (size_t)(m - 1)];
    }
    const float* wrb = wr + ((size_t)(j * 8 + h)) * 4096;
    const float* wib = wi + ((size_t)(j * 8 + h)) * 4096;
#pragma unroll
    for (int i = 0; i < 16; ++i) {
        const int t = tid + 256 * i;
        wrs[t] = wrb[t];
        wis[t] = wib[t];
    }
    lds_barrier();

    const int bl = tid >> 6;   // 0..3
    const int f  = tid & 63;   // 0..63
    const float2* xrow = &xs[bl * 64];
    float yr = 0.f, yi = 0.f;
#pragma unroll
    for (int e = 0; e < 64; e += 4) {
        const float4 xa = *(const float4*)&xrow[e];      // xs[e], xs[e+1] (wave-uniform addr)
        const float4 xb = *(const float4*)&xrow[e + 2];  // xs[e+2], xs[e+3]
        const float2 xv[4] = {make_float2(xa.x, xa.y), make_float2(xa.z, xa.w),
                              make_float2(xb.x, xb.y), make_float2(xb.z, xb.w)};
#pragma unroll
        for (int d = 0; d < 4; ++d) {
            const float a = wrs[(e + d) * 64 + f], cc = wis[(e + d) * 64 + f];
            yr = __builtin_fmaf(xv[d].x, a, yr); yr = __builtin_fmaf(-xv[d].y, cc, yr);
            yi = __builtin_fmaf(xv[d].x, cc, yi); yi = __builtin_fmaf( xv[d].y, a, yi);
        }
    }
    const int b = bq * 4 + bl;
    Y[((size_t)b * 64 + j) * 512 + (size_t)(h * 64 + f)] = make_float2(yr, yi);
}

// ---------------- synthesis with full w-symmetry: 1 rotator -> 4 output rows -------------------
//   out(l)      = F0+F1+F2+F3          out(l+2048) = F0-F1+F2-F3
//   out(l+1024) = (F0-F2)-(H1-H3)      out(l+3072) = (F0-F2)+(H1-H3)
__global__ __launch_bounds__(256, 4) void k_synth(const float2* __restrict__ Y,
                                                  const float2* __restrict__ trig,
                                                  float* __restrict__ out) {
    __shared__ __align__(16) float2 ys[64][32];  // 16 KB, pre-scaled

    const int tid = threadIdx.x;
    const int bi  = blockIdx.x;
    const int b   = bi >> 8;         // 16
    const int hft = (bi >> 4) & 15;  // 16
    const int lt  = bi & 15;         // 16

    const float invN = 1.0f / 4096.0f;
    const float2* yb = Y + (size_t)b * 64 * 512 + (size_t)hft * 32;
    for (int t = tid; t < 64 * 32; t += NTHREADS) {
        int j = t >> 5, cc = t & 31;
        float2 y = yb[(size_t)j * 512 + cc];
        if (j == 0) ys[0][cc] = make_float2(y.x * invN, 0.0f);
        else        ys[j][cc] = make_float2(y.x * (2.0f * invN), y.y * (2.0f * invN));
    }
    lds_barrier();

    const int r = tid >> 3;          // 0..31
    const int c = tid & 7;           // 0..7
    const int l0 = lt * 64 + r * 2;  // base l (v=0) in [0, 1024)

    float2 rot[2], w[2];
#pragma unroll
    for (int v = 0; v < 2; ++v) {
        w[v] = trig[(l0 + v) & 4095];
        rot[v] = make_float2(1.0f, 0.0f);
    }

    float F0[2][4], F1[2][4], F2[2][4], F3[2][4], H1[2][4], H3[2][4];
#pragma unroll
    for (int v = 0; v < 2; ++v)
#pragma unroll
        for (int u = 0; u < 4; ++u) {
            F0[v][u] = F1[v][u] = F2[v][u] = F3[v][u] = 0.0f;
            H1[v][u] = H3[v][u] = 0.0f;
        }

#define LOAD_YV(JROW)                                                        \
    float2 yv[4];                                                            \
    {                                                                        \
        const float4 ta = *(const float4*)&ys[(JROW)][c * 2];                \
        const float4 tb = *(const float4*)&ys[(JROW)][c * 2 + 16];           \
        yv[0] = make_float2(ta.x, ta.y); yv[1] = make_float2(ta.z, ta.w);    \
        yv[2] = make_float2(tb.x, tb.y); yv[3] = make_float2(tb.z, tb.w);    \
    }

    for (int j = 0; j < 64; j += 4) {
        {
            LOAD_YV(j)
#pragma unroll
            for (int v = 0; v < 2; ++v) {
                const float cx = rot[v].x, sx = rot[v].y;
#pragma unroll
                for (int u = 0; u < 4; ++u) {
                    float a = F0[v][u];
                    a = __builtin_fmaf(cx, yv[u].x, a);
                    a = __builtin_fmaf(-sx, yv[u].y, a);
                    F0[v][u] = a;
                }
                float nx = __builtin_fmaf(rot[v].x, w[v].x, -(rot[v].y * w[v].y));
                float ny = __builtin_fmaf(rot[v].x, w[v].y,  (rot[v].y * w[v].x));
                rot[v] = make_float2(nx, ny);
            }
        }
        {
            LOAD_YV(j + 1)
#pragma unroll
            for (int v = 0; v < 2; ++v) {
                const float cx = rot[v].x, sx = rot[v].y;
#pragma unroll
                for (int u = 0; u < 4; ++u) {
                    float a = F1[v][u], g = H1[v][u];
                    a = __builtin_fmaf(cx, yv[u].x, a);
                    a = __builtin_fmaf(-sx, yv[u].y, a);
                    g = __builtin_fmaf(sx, yv[u].x, g);
                    g = __builtin_fmaf(cx, yv[u].y, g);
                    F1[v][u] = a; H1[v][u] = g;
                }
                float nx = __builtin_fmaf(rot[v].x, w[v].x, -(rot[v].y * w[v].y));
                float ny = __builtin_fmaf(rot[v].x, w[v].y,  (rot[v].y * w[v].x));
                rot[v] = make_float2(nx, ny);
            }
        }
        {
            LOAD_YV(j + 2)
#pragma unroll
            for (int v = 0; v < 2; ++v) {
                const float cx = rot[v].x, sx = rot[v].y;
#pragma unroll
                for (int u = 0; u < 4; ++u) {
                    float a = F2[v][u];
                    a = __builtin_fmaf(cx, yv[u].x, a);
                    a = __builtin_fmaf(-sx, yv[u].y, a);
                    F2[v][u] = a;
                }
                float nx = __builtin_fmaf(rot[v].x, w[v].x, -(rot[v].y * w[v].y));
                float ny = __builtin_fmaf(rot[v].x, w[v].y,  (rot[v].y * w[v].x));
                rot[v] = make_float2(nx, ny);
            }
        }
        {
            LOAD_YV(j + 3)
#pragma unroll
            for (int v = 0; v < 2; ++v) {
                const float cx = rot[v].x, sx = rot[v].y;
#pragma unroll
                for (int u = 0; u < 4; ++u) {
                    float a = F3[v][u], g = H3[v][u];
                    a = __builtin_fmaf(cx, yv[u].x, a);
                    a = __builtin_fmaf(-sx, yv[u].y, a);
                    g = __builtin_fmaf(sx, yv[u].x, g);
                    g = __builtin_fmaf(cx, yv[u].y, g);
                    F3[v][u] = a; H3[v][u] = g;
                }
                float nx = __builtin_fmaf(rot[v].x, w[v].x, -(rot[v].y * w[v].y));
                float ny = __builtin_fmaf(rot[v].x, w[v].y,  (rot[v].y * w[v].x));
                rot[v] = make_float2(nx, ny);
            }
        }
    }
#undef LOAD_YV

#pragma unroll
    for (int v = 0; v < 2; ++v) {
        float* o0 = out + ((size_t)(b * 4096 + l0 + v)) * 512 + (size_t)hft * 32;
        float* o1 = o0 + (size_t)1024 * 512;
        float* o2 = o0 + (size_t)2048 * 512;
        float* o3 = o0 + (size_t)3072 * 512;
#pragma unroll
        for (int k = 0; k < 2; ++k) {
            float2 s0, s1, s2, s3;
#pragma unroll
            for (int d = 0; d < 2; ++d) {
                const int u = 2 * k + d;
                const float p = F0[v][u] + F2[v][u];
                const float m = F0[v][u] - F2[v][u];
                const float q = F1[v][u] + F3[v][u];
                const float hh = H3[v][u] - H1[v][u];
                ((float*)&s0)[d] = p + q;
                ((float*)&s2)[d] = p - q;
                ((float*)&s1)[d] = m + hh;
                ((float*)&s3)[d] = m - hh;
            }
            *(float2*)(o0 + k * 16 + c * 2) = s0;
            *(float2*)(o1 + k * 16 + c * 2) = s1;
            *(float2*)(o2 + k * 16 + c * 2) = s2;
            *(float2*)(o3 + k * 16 + c * 2) = s3;
        }
    }
}

// ---------------- launch ----------------
extern "C" void kernel_launch(void* const* d_in, const int* in_sizes, int n_in,
                              void* d_out, int out_size, void* d_ws, size_t ws_size,
                              hipStream_t stream) {
    const float* q  = (const float*)d_in[0];
    const float* wr = (const float*)d_in[3];
    const float* wi = (const float*)d_in[4];

    char* ws = (char*)d_ws;
    float2*             trig  = (float2*)(ws + 0);                  // 32 KB
    unsigned long long* score = (unsigned long long*)(ws + 32768);  // 16 KB
    int*                idx   = (int*)(ws + 49152);                 // 256 B
    float2*             Y     = (float2*)(ws + 65536);              // 4 MB

    // d_out triples as: transposed-q scratch T -> spectrum Xout (in-place) -> final output.
    float2* Xs = (float2*)d_out;

    k_tables<<<16, 256, 0, stream>>>(trig, score);     // tables + score zeroing (no memset)
    k_xpose<<<4096, 256, 0, stream>>>(q, Xs);          // (b:16, h:8, c5:32), 128-row tiles
    k_fft<<<1024, 256, 0, stream>>>(trig, Xs, score);  // radix-16 x3, 4 planes/block
    k_topk<<<8, 256, 0, stream>>>(score, idx);         // 2048 candidates, 1/thread
    k_proj<<<2048, 256, 0, stream>>>(Xs, wr, wi, idx, Y);  // (j:64, h:8, bq:4)
    k_synth<<<4096, 256, 0, stream>>>(Y, trig, (float*)d_out);  // (b:16, hft:16, lt:16)
}

// Round 18
// 234.676 us; speedup vs baseline: 1.3205x; 1.0308x over previous
//
#include <hip/hip_runtime.h>

// Problem constants: B=16, L=4096, H=8, E=64, K=64, F=2049 (rfft bins)
// Only bins m in [1,2048] matter (bin 0 excluded from top-k; out_ft uses slots 0..63).

#define NTHREADS 256

typedef _Float16 f16x8 __attribute__((ext_vector_type(8)));
typedef float    f32x4 __attribute__((ext_vector_type(4)));

// LDS-only barrier: drains LDS ops (lgkmcnt) but leaves global loads/stores in flight.
__device__ inline void lds_barrier() {
    asm volatile("s_waitcnt lgkmcnt(0)" ::: "memory");
    __builtin_amdgcn_s_barrier();
}

// LDS swizzle for the FFT working array: flips bits 1-3 by bits 4-6 (bijective, disjoint).
// Preserves bit 0, so (2s, 2s+1) pairs stay contiguous -> b128 pair stores are legal.
#define ZI(i) ((i) ^ ((((i) >> 4) & 7) << 1))

__device__ inline float2 f2add(float2 a, float2 b) { return make_float2(a.x + b.x, a.y + b.y); }
__device__ inline float2 f2sub(float2 a, float2 b) { return make_float2(a.x - b.x, a.y - b.y); }
// complex mul, exactly 4 VALU (mul, fma, mul, fma)
__device__ inline float2 cmulf(float2 a, float2 b) {
    return make_float2(__builtin_fmaf(a.x, b.x, -(a.y * b.y)),
                       __builtin_fmaf(a.x, b.y,  a.y * b.x));
}

// radix-16 DIT butterfly on 16 points (4 stages st..st+3 in registers).
__device__ inline void radix16(float2 x[16], float2 tA, float2 tB, float2 tC, float2 tD) {
#pragma unroll
    for (int q = 0; q < 8; ++q) {
        float2 v = cmulf(tA, x[2 * q + 1]);
        float2 u = x[2 * q];
        x[2 * q]     = f2add(u, v);
        x[2 * q + 1] = f2sub(u, v);
    }
    {
        float2 tB1 = make_float2(tB.y, -tB.x);
#pragma unroll
        for (int q = 0; q < 4; ++q) {
            {
                float2 v = cmulf(tB, x[4 * q + 2]);
                float2 u = x[4 * q];
                x[4 * q]     = f2add(u, v);
                x[4 * q + 2] = f2sub(u, v);
            }
            {
                float2 v = cmulf(tB1, x[4 * q + 3]);
                float2 u = x[4 * q + 1];
                x[4 * q + 1] = f2add(u, v);
                x[4 * q + 3] = f2sub(u, v);
            }
        }
    }
    {
        const float C = 0.70710678118654752f;
        float2 w0 = tC;
        float2 w1 = cmulf(tC, make_float2(C, -C));
        float2 w2 = make_float2(tC.y, -tC.x);
        float2 w3 = cmulf(tC, make_float2(-C, -C));
#pragma unroll
        for (int q = 0; q < 2; ++q) {
            float2 ws[4] = {w0, w1, w2, w3};
#pragma unroll
            for (int r = 0; r < 4; ++r) {
                float2 v = cmulf(ws[r], x[8 * q + r + 4]);
                float2 u = x[8 * q + r];
                x[8 * q + r]     = f2add(u, v);
                x[8 * q + r + 4] = f2sub(u, v);
            }
        }
    }
    {
        const float C  = 0.70710678118654752f;
        const float C1 = 0.92387953251128676f;  // cos(pi/8)
        const float S1 = 0.38268343236508977f;  // sin(pi/8)
        float2 wD[8];
        wD[0] = tD;
        wD[1] = cmulf(tD, make_float2(C1, -S1));
        wD[2] = cmulf(tD, make_float2(C, -C));
        wD[3] = cmulf(tD, make_float2(S1, -C1));
        wD[4] = make_float2(tD.y, -tD.x);
        wD[5] = cmulf(tD, make_float2(-S1, -C1));
        wD[6] = cmulf(tD, make_float2(-C, -C));
        wD[7] = cmulf(tD, make_float2(-C1, -S1));
#pragma unroll
        for (int r = 0; r < 8; ++r) {
            float2 v = cmulf(wD[r], x[r + 8]);
            float2 u = x[r];
            x[r]     = f2add(u, v);
            x[r + 8] = f2sub(u, v);
        }
    }
}

// ---------------- tables + score zeroing ------------------------------------------------------
__global__ void k_tables(float2* __restrict__ trig, unsigned long long* __restrict__ score) {
    int k = blockIdx.x * blockDim.x + threadIdx.x;
    if (k < 4096) {
        double th = (6.283185307179586476925286766559 * (double)k) / 4096.0;
        trig[k] = make_float2((float)cos(th), (float)sin(th));
    }
    if (k < 2048) score[k] = 0ULL;
}

// ---------------- fp16 synthesis matrix: Af[l][k] = k<64 ? cos(2pi k l/N) : -sin(2pi (k-64) l/N)
__global__ __launch_bounds__(256) void k_af(const float2* __restrict__ trig,
                                            _Float16* __restrict__ Af) {
    const int gid = blockIdx.x * 256 + threadIdx.x;  // 524288 total
    const int l = gid >> 7, k = gid & 127;
    float v = (k < 64) ? trig[(k * l) & 4095].x : -trig[((k - 64) * l) & 4095].y;
    Af[gid] = (_Float16)v;
}

// ---------------- transpose + bit-reversal: q[b,l,h,e] -> T[(b,h,eo)][p][j] (float2) -----------
__global__ __launch_bounds__(256) void k_xpose(const float* __restrict__ q,
                                               float2* __restrict__ T) {
    __shared__ float tile[128][65];  // 33 KB, padded (+1)

    const int tid = threadIdx.x;
    const int bi  = blockIdx.x;
    const int b   = bi >> 8;
    const int h   = (bi >> 5) & 7;
    const int c5  = bi & 31;

    const float* qb = q + ((size_t)b * 4096 * 512) + (size_t)h * 64;
#pragma unroll
    for (int i = 0; i < 8; ++i) {
        const int f = tid + 256 * i;
        const int t = f >> 4, e4 = f & 15;
        const float4 v = *(const float4*)(qb + (size_t)(c5 + 32 * t) * 512 + e4 * 4);
        tile[t][e4 * 4 + 0] = v.x;
        tile[t][e4 * 4 + 1] = v.y;
        tile[t][e4 * 4 + 2] = v.z;
        tile[t][e4 * 4 + 3] = v.w;
    }
    lds_barrier();

    const int wave = tid >> 6, lane = tid & 63;
    const int rl  = __brev(lane) >> 26;  // rev6(lane)
    const int r5c = __brev(c5) >> 27;    // rev5(c5)
    for (int cc = wave; cc < 32; cc += 4) {
        const int eo = cc >> 2, p = cc & 3;
        const int col0 = eo * 8 + 2 * p;
        float2* dst = T + ((size_t)((b * 8 + h) * 8 + eo)) * 16384 + (size_t)p * 4096
                        + (size_t)r5c * 128;
        float4 o;
        o.x = tile[rl][col0];      o.y = tile[rl][col0 + 1];
        o.z = tile[rl + 64][col0]; o.w = tile[rl + 64][col0 + 1];
        *(float4*)(dst + 2 * lane) = o;  // 16B/lane, contiguous 1KB run per (eo,p)
    }
}

// ---------------- FFT (3 x radix-16 passes) + spectrum store + score accumulation --------------
__global__ __launch_bounds__(256) void k_fft(const float2* __restrict__ trig,
                                             float2* __restrict__ Xout,
                                             unsigned long long* __restrict__ score) {
    __shared__ float2 z[4096];    // 32 KB (swizzled indexing)
    __shared__ float2 ctw4[80];   // pass1 quads, stride-5 layout (conflict-free mod 16)

    const int tid = threadIdx.x;
    const int bi  = blockIdx.x;

    if (tid < 64) {
        const int j = tid >> 2, qq = tid & 3;
        float2 a = trig[j << (7 - qq)];
        ctw4[5 * j + qq] = make_float2(a.x, -a.y);
    }

    float eaccr[8];
#pragma unroll
    for (int k = 0; k < 8; ++k) eaccr[k] = 0.f;

    const float2 ONE = make_float2(1.0f, 0.0f);
    const float2* base = Xout + (size_t)bi * 16384;

    float4 pre[8];
#pragma unroll
    for (int g = 0; g < 8; ++g) pre[g] = *(const float4*)(base + 16 * tid + 2 * g);
    lds_barrier();  // ctw4 ready (prefetch loads stay in flight)

    for (int p = 0; p < 4; ++p) {
        float2 x[16];
#pragma unroll
        for (int g = 0; g < 8; ++g) {
            x[2 * g]     = make_float2(pre[g].x, pre[g].y);
            x[2 * g + 1] = make_float2(pre[g].z, pre[g].w);
        }
        if (p < 3) {
            const float2* pn = base + (size_t)(p + 1) * 4096;
#pragma unroll
            for (int g = 0; g < 8; ++g) pre[g] = *(const float4*)(pn + 16 * tid + 2 * g);
        }

        radix16(x, ONE, ONE, ONE, ONE);
        {
            const int i0 = 16 * tid;
#pragma unroll
            for (int s = 0; s < 8; ++s) {
                *(float4*)&z[ZI(i0 + 2 * s)] = make_float4(x[2 * s].x, x[2 * s].y,
                                                           x[2 * s + 1].x, x[2 * s + 1].y);
            }
        }
        lds_barrier();

        // pass 1: st=5, h=16
        {
            const int j = tid & 15;
            const int g = tid >> 4;
            const int i0 = (g << 8) + j;
            int ad[16];
#pragma unroll
            for (int k = 0; k < 16; ++k) ad[k] = ZI(i0 + 16 * k);
#pragma unroll
            for (int k = 0; k < 16; ++k) x[k] = z[ad[k]];
            const float2 tA = ctw4[5 * j + 0];
            const float2 tB = ctw4[5 * j + 1];
            const float2 tC = ctw4[5 * j + 2];
            const float2 tD = ctw4[5 * j + 3];
            radix16(x, tA, tB, tC, tD);
#pragma unroll
            for (int k = 0; k < 16; ++k) z[ad[k]] = x[k];
        }
        lds_barrier();

        // pass 2: st=9, h=256
        {
            const int j = tid;
            int ad[16];
#pragma unroll
            for (int k = 0; k < 16; ++k) ad[k] = ZI(j + 256 * k);
#pragma unroll
            for (int k = 0; k < 16; ++k) x[k] = z[ad[k]];
            float2 a = trig[j << 3], b2 = trig[j << 2], c = trig[j << 1], d = trig[j];
            const float2 tA = make_float2(a.x, -a.y);
            const float2 tB = make_float2(b2.x, -b2.y);
            const float2 tC = make_float2(c.x, -c.y);
            const float2 tD = make_float2(d.x, -d.y);
            radix16(x, tA, tB, tC, tD);
#pragma unroll
            for (int k = 0; k < 16; ++k) z[ad[k]] = x[k];
        }
        lds_barrier();

        // unpack two real spectra; store; accumulate energy
        {
            const size_t s0 = (size_t)bi * 16384 + (size_t)p * 4096;
#pragma unroll
            for (int k = 0; k < 8; ++k) {
                const int t = tid + 256 * k;
                const int m = t + 1;
                float2 Za = z[ZI(m)];
                float2 Zb = z[ZI(4096 - m)];
                float Xr0 = 0.5f * (Za.x + Zb.x);
                float Xi0 = 0.5f * (Za.y - Zb.y);
                float Xr1 = 0.5f * (Za.y + Zb.y);
                float Xi1 = 0.5f * (Zb.x - Za.x);
                Xout[s0 + t]        = make_float2(Xr0, Xi0);
                Xout[s0 + 2048 + t] = make_float2(Xr1, Xi1);
                eaccr[k] += Xr0 * Xr0 + Xi0 * Xi0 + Xr1 * Xr1 + Xi1 * Xi1;
            }
        }
        lds_barrier();
    }

#pragma unroll
    for (int k = 0; k < 8; ++k) {
        unsigned long long v = (unsigned long long)llrintf(eaccr[k] * 1048576.0f);  // 2^20
        atomicAdd(&score[tid + 256 * k], v);
    }
}

// ---------------- top-64, parallelized: 8 blocks x 256 threads -------------------------------
__global__ __launch_bounds__(256) void k_topk(const unsigned long long* __restrict__ score,
                                              int* __restrict__ idx) {
    __shared__ unsigned long long s[2048];
    const int tid = threadIdx.x;
    for (int t = tid; t < 2048; t += 256) s[t] = score[t];
    __syncthreads();

    const int t = blockIdx.x * 256 + tid;  // 0..2047
    const unsigned long long my = s[t];
    int rank = 0;
#pragma unroll 8
    for (int u = 0; u < 2048; ++u) {
        unsigned long long o = s[u];
        rank += (int)((o > my) || (o == my && u < t));
    }
    if (rank < 64) idx[rank] = t + 1;  // store frequency index m
}

// ---------------- gather + projection -> fp16 Bt for the MFMA synth ---------------------------
// Yt[b][hf][k]: k<64 -> Yr[b,j=k,hf] (j=0 pre-halved); k>=64 -> Yi[b,j=k-64,hf].
__global__ __launch_bounds__(256) void k_proj(const float2* __restrict__ X,
                                              const float* __restrict__ wr,
                                              const float* __restrict__ wi,
                                              const int* __restrict__ idx,
                                              _Float16* __restrict__ Yt) {
    __shared__ __align__(16) float2 xs[4 * 64];  // [b_loc][e]  2 KB
    __shared__ float  wrs[64 * 64];              // [e][f] 16 KB
    __shared__ float  wis[64 * 64];              // 16 KB

    const int tid = threadIdx.x;
    const int j  = blockIdx.x >> 5;
    const int h  = (blockIdx.x >> 2) & 7;
    const int bq = blockIdx.x & 3;
    const int m = idx[j];

    {
        const int bl = tid >> 6, e = tid & 63;
        xs[tid] = X[((size_t)(((bq * 4 + bl) * 8 + h) * 64 + e)) * 2048 + (size_t)(m - 1)];
    }
    const float* wrb = wr + ((size_t)(j * 8 + h)) * 4096;
    const float* wib = wi + ((size_t)(j * 8 + h)) * 4096;
#pragma unroll
    for (int i = 0; i < 16; ++i) {
        const int t = tid + 256 * i;
        wrs[t] = wrb[t];
        wis[t] = wib[t];
    }
    lds_barrier();

    const int bl = tid >> 6;   // 0..3
    const int f  = tid & 63;   // 0..63
    const float2* xrow = &xs[bl * 64];
    float yr = 0.f, yi = 0.f;
#pragma unroll
    for (int e = 0; e < 64; e += 4) {
        const float4 xa = *(const float4*)&xrow[e];
        const float4 xb = *(const float4*)&xrow[e + 2];
        const float2 xv[4] = {make_float2(xa.x, xa.y), make_float2(xa.z, xa.w),
                              make_float2(xb.x, xb.y), make_float2(xb.z, xb.w)};
#pragma unroll
        for (int d = 0; d < 4; ++d) {
            const float a = wrs[(e + d) * 64 + f], cc = wis[(e + d) * 64 + f];
            yr = __builtin_fmaf(xv[d].x, a, yr); yr = __builtin_fmaf(-xv[d].y, cc, yr);
            yi = __builtin_fmaf(xv[d].x, cc, yi); yi = __builtin_fmaf( xv[d].y, a, yi);
        }
    }
    const int b  = bq * 4 + bl;
    const int hf = h * 64 + f;
    _Float16* yt = Yt + ((size_t)b * 512 + (size_t)hf) * 128;
    yt[j]      = (_Float16)(j == 0 ? 0.5f * yr : yr);
    yt[64 + j] = (_Float16)yi;
}

// ---------------- MFMA synthesis: out[b, l, hf] = (2/N) * sum_k Af[l,k] * Yt[b,hf,k] ----------
// grid: 4096 blocks = (b:16, ng:4, lt:64). Block: 64 l x 128 hf, K=128. 4 waves, each 64x32.
// Fragment layouts (verified m89): A lane: row=lane&15, k=(lane>>4)*8+i (16B contiguous);
// B lane: col=lane&15 (Bt row), same k slice; C/D: col=lane&15, row=(lane>>4)*4+r.
__global__ __launch_bounds__(256) void k_synth(const _Float16* __restrict__ Af,
                                               const _Float16* __restrict__ Yt,
                                               float* __restrict__ out) {
    const int tid  = threadIdx.x;
    const int wv   = tid >> 6;
    const int lane = tid & 63;
    const int bi   = blockIdx.x;
    const int b    = bi >> 8;         // 16
    const int ng   = (bi >> 6) & 3;   // 4
    const int lt   = bi & 63;         // 64

    const int l0 = lt * 64;
    const int n0 = ng * 128 + wv * 32;

    const int row = lane & 15;        // A-row / B-col / C-col
    const int kb  = lane >> 4;        // k-block 0..3

    f32x4 acc[4][2] = {};

    const _Float16* Ab = Af + (size_t)l0 * 128;
    const _Float16* Bb = Yt + (size_t)b * 512 * 128 + (size_t)n0 * 128;

#pragma unroll
    for (int k0 = 0; k0 < 128; k0 += 32) {
        f16x8 a[4], bf[2];
#pragma unroll
        for (int mt = 0; mt < 4; ++mt)
            a[mt] = *(const f16x8*)(Ab + (size_t)(mt * 16 + row) * 128 + k0 + kb * 8);
#pragma unroll
        for (int nt = 0; nt < 2; ++nt)
            bf[nt] = *(const f16x8*)(Bb + (size_t)(nt * 16 + row) * 128 + k0 + kb * 8);
#pragma unroll
        for (int mt = 0; mt < 4; ++mt)
#pragma unroll
            for (int nt = 0; nt < 2; ++nt)
                acc[mt][nt] = __builtin_amdgcn_mfma_f32_16x16x32_f16(a[mt], bf[nt],
                                                                     acc[mt][nt], 0, 0, 0);
    }

    const float s = 2.0f / 4096.0f;
#pragma unroll
    for (int mt = 0; mt < 4; ++mt) {
#pragma unroll
        for (int nt = 0; nt < 2; ++nt) {
            const int col = n0 + nt * 16 + row;  // hf
#pragma unroll
            for (int r = 0; r < 4; ++r) {
                const int mrow = mt * 16 + kb * 4 + r;
                out[((size_t)(b * 4096 + l0 + mrow)) * 512 + col] = acc[mt][nt][r] * s;
            }
        }
    }
}

// ---------------- launch ----------------
extern "C" void kernel_launch(void* const* d_in, const int* in_sizes, int n_in,
                              void* d_out, int out_size, void* d_ws, size_t ws_size,
                              hipStream_t stream) {
    const float* q  = (const float*)d_in[0];
    const float* wr = (const float*)d_in[3];
    const float* wi = (const float*)d_in[4];

    char* ws = (char*)d_ws;
    float2*             trig  = (float2*)(ws + 0);                  // 32 KB
    unsigned long long* score = (unsigned long long*)(ws + 32768);  // 16 KB
    int*                idx   = (int*)(ws + 49152);                 // 256 B
    _Float16*           Af    = (_Float16*)(ws + 65536);            // 1 MB
    _Float16*           Yt    = (_Float16*)(ws + 65536 + 1048576);  // 2 MB

    // d_out triples as: transposed-q scratch T -> spectrum Xout (in-place) -> final output.
    float2* Xs = (float2*)d_out;

    k_tables<<<16, 256, 0, stream>>>(trig, score);     // tables + score zeroing
    k_af<<<2048, 256, 0, stream>>>(trig, Af);          // fp16 synthesis matrix
    k_xpose<<<4096, 256, 0, stream>>>(q, Xs);          // (b:16, h:8, c5:32), 128-row tiles
    k_fft<<<1024, 256, 0, stream>>>(trig, Xs, score);  // radix-16 x3, 4 planes/block
    k_topk<<<8, 256, 0, stream>>>(score, idx);         // 2048 candidates, 1/thread
    k_proj<<<2048, 256, 0, stream>>>(Xs, wr, wi, idx, Yt);      // -> fp16 Bt
    k_synth<<<4096, 256, 0, stream>>>(Af, Yt, (float*)d_out);   // MFMA GEMM
}

// Round 20
// 228.575 us; speedup vs baseline: 1.3557x; 1.0267x over previous
//
#include <hip/hip_runtime.h>
#include <hip/hip_fp16.h>

// Problem constants: B=16, L=4096, H=8, E=64, K=64, F=2049 (rfft bins)
// Only bins m in [1,2048] matter (bin 0 excluded from top-k; out_ft uses slots 0..63).

#define NTHREADS 256

typedef _Float16 f16x8 __attribute__((ext_vector_type(8)));
typedef float    f32x4 __attribute__((ext_vector_type(4)));

// LDS-only barrier: drains LDS ops (lgkmcnt) but leaves global loads/stores in flight.
__device__ inline void lds_barrier() {
    asm volatile("s_waitcnt lgkmcnt(0)" ::: "memory");
    __builtin_amdgcn_s_barrier();
}

// LDS swizzle for the FFT working array: flips bits 1-3 by bits 4-6 (bijective, disjoint).
// Preserves bit 0, so (2s, 2s+1) pairs stay contiguous -> b128 pair stores are legal.
#define ZI(i) ((i) ^ ((((i) >> 4) & 7) << 1))

__device__ inline float2 f2add(float2 a, float2 b) { return make_float2(a.x + b.x, a.y + b.y); }
__device__ inline float2 f2sub(float2 a, float2 b) { return make_float2(a.x - b.x, a.y - b.y); }
// complex mul, exactly 4 VALU (mul, fma, mul, fma)
__device__ inline float2 cmulf(float2 a, float2 b) {
    return make_float2(__builtin_fmaf(a.x, b.x, -(a.y * b.y)),
                       __builtin_fmaf(a.x, b.y,  a.y * b.x));
}

// radix-16 DIT butterfly on 16 points (4 stages st..st+3 in registers).
__device__ inline void radix16(float2 x[16], float2 tA, float2 tB, float2 tC, float2 tD) {
#pragma unroll
    for (int q = 0; q < 8; ++q) {
        float2 v = cmulf(tA, x[2 * q + 1]);
        float2 u = x[2 * q];
        x[2 * q]     = f2add(u, v);
        x[2 * q + 1] = f2sub(u, v);
    }
    {
        float2 tB1 = make_float2(tB.y, -tB.x);
#pragma unroll
        for (int q = 0; q < 4; ++q) {
            {
                float2 v = cmulf(tB, x[4 * q + 2]);
                float2 u = x[4 * q];
                x[4 * q]     = f2add(u, v);
                x[4 * q + 2] = f2sub(u, v);
            }
            {
                float2 v = cmulf(tB1, x[4 * q + 3]);
                float2 u = x[4 * q + 1];
                x[4 * q + 1] = f2add(u, v);
                x[4 * q + 3] = f2sub(u, v);
            }
        }
    }
    {
        const float C = 0.70710678118654752f;
        float2 w0 = tC;
        float2 w1 = cmulf(tC, make_float2(C, -C));
        float2 w2 = make_float2(tC.y, -tC.x);
        float2 w3 = cmulf(tC, make_float2(-C, -C));
#pragma unroll
        for (int q = 0; q < 2; ++q) {
            float2 ws[4] = {w0, w1, w2, w3};
#pragma unroll
            for (int r = 0; r < 4; ++r) {
                float2 v = cmulf(ws[r], x[8 * q + r + 4]);
                float2 u = x[8 * q + r];
                x[8 * q + r]     = f2add(u, v);
                x[8 * q + r + 4] = f2sub(u, v);
            }
        }
    }
    {
        const float C  = 0.70710678118654752f;
        const float C1 = 0.92387953251128676f;  // cos(pi/8)
        const float S1 = 0.38268343236508977f;  // sin(pi/8)
        float2 wD[8];
        wD[0] = tD;
        wD[1] = cmulf(tD, make_float2(C1, -S1));
        wD[2] = cmulf(tD, make_float2(C, -C));
        wD[3] = cmulf(tD, make_float2(S1, -C1));
        wD[4] = make_float2(tD.y, -tD.x);
        wD[5] = cmulf(tD, make_float2(-S1, -C1));
        wD[6] = cmulf(tD, make_float2(-C, -C));
        wD[7] = cmulf(tD, make_float2(-C1, -S1));
#pragma unroll
        for (int r = 0; r < 8; ++r) {
            float2 v = cmulf(wD[r], x[r + 8]);
            float2 u = x[r];
            x[r]     = f2add(u, v);
            x[r + 8] = f2sub(u, v);
        }
    }
}

// ---------------- init: trig (f64-accurate) + score zeroing + fp16 Af matrix ------------------
__global__ __launch_bounds__(256) void k_init(float2* __restrict__ trig,
                                              unsigned long long* __restrict__ score,
                                              _Float16* __restrict__ Af) {
    const int g = blockIdx.x * 256 + threadIdx.x;
    if (g < 4096) {
        double th = (6.283185307179586476925286766559 * (double)g) / 4096.0;
        trig[g] = make_float2((float)cos(th), (float)sin(th));
        if (g < 2048) score[g] = 0ULL;
    } else {
        const int gid = g - 4096;           // 0 .. 524287
        const int l = gid >> 7, k = gid & 127;
        const int kk = (k < 64) ? k : k - 64;
        const int ph = (kk * l) & 4095;
        const float th = 1.5339807878856412e-3f * (float)ph;  // 2*pi/4096
        float v = (k < 64) ? __cosf(th) : -__sinf(th);
        Af[gid] = (_Float16)v;
    }
}

// ---------------- transpose + bit-reversal: q[b,l,h,e] -> T[(b,h,eo)][p][j] (float2) -----------
__global__ __launch_bounds__(256) void k_xpose(const float* __restrict__ q,
                                               float2* __restrict__ T) {
    __shared__ float tile[128][65];  // 33 KB, padded (+1)

    const int tid = threadIdx.x;
    const int bi  = blockIdx.x;
    const int b   = bi >> 8;
    const int h   = (bi >> 5) & 7;
    const int c5  = bi & 31;

    const float* qb = q + ((size_t)b * 4096 * 512) + (size_t)h * 64;
#pragma unroll
    for (int i = 0; i < 8; ++i) {
        const int f = tid + 256 * i;
        const int t = f >> 4, e4 = f & 15;
        const float4 v = *(const float4*)(qb + (size_t)(c5 + 32 * t) * 512 + e4 * 4);
        tile[t][e4 * 4 + 0] = v.x;
        tile[t][e4 * 4 + 1] = v.y;
        tile[t][e4 * 4 + 2] = v.z;
        tile[t][e4 * 4 + 3] = v.w;
    }
    lds_barrier();

    const int wave = tid >> 6, lane = tid & 63;
    const int rl  = __brev(lane) >> 26;  // rev6(lane)
    const int r5c = __brev(c5) >> 27;    // rev5(c5)
    for (int cc = wave; cc < 32; cc += 4) {
        const int eo = cc >> 2, p = cc & 3;
        const int col0 = eo * 8 + 2 * p;
        float2* dst = T + ((size_t)((b * 8 + h) * 8 + eo)) * 16384 + (size_t)p * 4096
                        + (size_t)r5c * 128;
        float4 o;
        o.x = tile[rl][col0];      o.y = tile[rl][col0 + 1];
        o.z = tile[rl + 64][col0]; o.w = tile[rl + 64][col0 + 1];
        *(float4*)(dst + 2 * lane) = o;  // 16B/lane, contiguous 1KB run per (eo,p)
    }
}

// ---------------- FFT (3 x radix-16 passes) + fp16 spectrum store + score accumulation ---------
// Spectrum stored as half2 per bin IN THE SAME per-octet 128KB region as the block's own input:
// half2 index bi*32768 + p*4096 (+2048) = byte bi*128KB + p*16KB. Plane p's 16KB write lands in
// this block's already-consumed float2 bytes and never overlaps the in-flight prefetch of plane
// p+1 at [(p+1)*32KB, ...). No cross-block aliasing (the R19 bug).
__global__ __launch_bounds__(256) void k_fft(const float2* __restrict__ trig,
                                             float2* __restrict__ Xout,
                                             unsigned long long* __restrict__ score) {
    __shared__ float2 z[4096];    // 32 KB (swizzled indexing)
    __shared__ float2 ctw4[80];   // pass1 quads, stride-5 layout (conflict-free mod 16)

    const int tid = threadIdx.x;
    const int bi  = blockIdx.x;

    if (tid < 64) {
        const int j = tid >> 2, qq = tid & 3;
        float2 a = trig[j << (7 - qq)];
        ctw4[5 * j + qq] = make_float2(a.x, -a.y);
    }

    float eaccr[8];
#pragma unroll
    for (int k = 0; k < 8; ++k) eaccr[k] = 0.f;

    const float2 ONE = make_float2(1.0f, 0.0f);
    const float2* base = Xout + (size_t)bi * 16384;
    __half2* Xh = (__half2*)Xout;

    float4 pre[8];
#pragma unroll
    for (int g = 0; g < 8; ++g) pre[g] = *(const float4*)(base + 16 * tid + 2 * g);
    lds_barrier();  // ctw4 ready (prefetch loads stay in flight)

    for (int p = 0; p < 4; ++p) {
        float2 x[16];
#pragma unroll
        for (int g = 0; g < 8; ++g) {
            x[2 * g]     = make_float2(pre[g].x, pre[g].y);
            x[2 * g + 1] = make_float2(pre[g].z, pre[g].w);
        }
        if (p < 3) {
            const float2* pn = base + (size_t)(p + 1) * 4096;
#pragma unroll
            for (int g = 0; g < 8; ++g) pre[g] = *(const float4*)(pn + 16 * tid + 2 * g);
        }

        radix16(x, ONE, ONE, ONE, ONE);
        {
            const int i0 = 16 * tid;
#pragma unroll
            for (int s = 0; s < 8; ++s) {
                *(float4*)&z[ZI(i0 + 2 * s)] = make_float4(x[2 * s].x, x[2 * s].y,
                                                           x[2 * s + 1].x, x[2 * s + 1].y);
            }
        }
        lds_barrier();

        // pass 1: st=5, h=16
        {
            const int j = tid & 15;
            const int g = tid >> 4;
            const int i0 = (g << 8) + j;
            int ad[16];
#pragma unroll
            for (int k = 0; k < 16; ++k) ad[k] = ZI(i0 + 16 * k);
#pragma unroll
            for (int k = 0; k < 16; ++k) x[k] = z[ad[k]];
            const float2 tA = ctw4[5 * j + 0];
            const float2 tB = ctw4[5 * j + 1];
            const float2 tC = ctw4[5 * j + 2];
            const float2 tD = ctw4[5 * j + 3];
            radix16(x, tA, tB, tC, tD);
#pragma unroll
            for (int k = 0; k < 16; ++k) z[ad[k]] = x[k];
        }
        lds_barrier();

        // pass 2: st=9, h=256
        {
            const int j = tid;
            int ad[16];
#pragma unroll
            for (int k = 0; k < 16; ++k) ad[k] = ZI(j + 256 * k);
#pragma unroll
            for (int k = 0; k < 16; ++k) x[k] = z[ad[k]];
            float2 a = trig[j << 3], b2 = trig[j << 2], c = trig[j << 1], d = trig[j];
            const float2 tA = make_float2(a.x, -a.y);
            const float2 tB = make_float2(b2.x, -b2.y);
            const float2 tC = make_float2(c.x, -c.y);
            const float2 tD = make_float2(d.x, -d.y);
            radix16(x, tA, tB, tC, tD);
#pragma unroll
            for (int k = 0; k < 16; ++k) z[ad[k]] = x[k];
        }
        lds_barrier();

        // unpack two real spectra; fp16 store (own-region layout); f32 energy accumulation
        {
            const size_t s0 = (size_t)bi * 32768 + (size_t)p * 4096;  // half2 idx, own 128KB region
#pragma unroll
            for (int k = 0; k < 8; ++k) {
                const int t = tid + 256 * k;
                const int m = t + 1;
                float2 Za = z[ZI(m)];
                float2 Zb = z[ZI(4096 - m)];
                float Xr0 = 0.5f * (Za.x + Zb.x);
                float Xi0 = 0.5f * (Za.y - Zb.y);
                float Xr1 = 0.5f * (Za.y + Zb.y);
                float Xi1 = 0.5f * (Zb.x - Za.x);
                Xh[s0 + t]        = __floats2half2_rn(Xr0, Xi0);
                Xh[s0 + 2048 + t] = __floats2half2_rn(Xr1, Xi1);
                eaccr[k] += Xr0 * Xr0 + Xi0 * Xi0 + Xr1 * Xr1 + Xi1 * Xi1;
            }
        }
        lds_barrier();
    }

#pragma unroll
    for (int k = 0; k < 8; ++k) {
        unsigned long long v = (unsigned long long)llrintf(eaccr[k] * 1048576.0f);  // 2^20
        atomicAdd(&score[tid + 256 * k], v);
    }
}

// ---------------- top-64, parallelized: 8 blocks x 256 threads -------------------------------
__global__ __launch_bounds__(256) void k_topk(const unsigned long long* __restrict__ score,
                                              int* __restrict__ idx) {
    __shared__ unsigned long long s[2048];
    const int tid = threadIdx.x;
    for (int t = tid; t < 2048; t += 256) s[t] = score[t];
    __syncthreads();

    const int t = blockIdx.x * 256 + tid;  // 0..2047
    const unsigned long long my = s[t];
    int rank = 0;
#pragma unroll 8
    for (int u = 0; u < 2048; ++u) {
        unsigned long long o = s[u];
        rank += (int)((o > my) || (o == my && u < t));
    }
    if (rank < 64) idx[rank] = t + 1;  // store frequency index m
}

// ---------------- gather + projection -> fp16 Bt for the MFMA synth ---------------------------
// Spectrum layout (per-octet regions): half2 idx of (sig, bin) =
//   (sig>>3)*32768 + ((sig>>1)&3)*4096 + (sig&1)*2048 + bin.
// Yt[b][hf][k]: k<64 -> Yr[b,j=k,hf] (j=0 pre-halved); k>=64 -> Yi[b,j=k-64,hf].
__global__ __launch_bounds__(256) void k_proj(const __half2* __restrict__ Xh,
                                              const float* __restrict__ wr,
                                              const float* __restrict__ wi,
                                              const int* __restrict__ idx,
                                              _Float16* __restrict__ Yt) {
    __shared__ __align__(16) float2 xs[4 * 64];  // [b_loc][e]  2 KB
    __shared__ float  wrs[64 * 64];              // [e][f] 16 KB
    __shared__ float  wis[64 * 64];              // 16 KB

    const int tid = threadIdx.x;
    const int j  = blockIdx.x >> 5;
    const int h  = (blockIdx.x >> 2) & 7;
    const int bq = blockIdx.x & 3;
    const int m = idx[j];

    {
        const int bl = tid >> 6, e = tid & 63;
        const int sig = (((bq * 4 + bl) * 8 + h) * 64 + e);
        const size_t xi = (size_t)(sig >> 3) * 32768 + (size_t)((sig >> 1) & 3) * 4096
                        + (size_t)(sig & 1) * 2048 + (size_t)(m - 1);
        xs[tid] = __half22float2(Xh[xi]);
    }
    const float* wrb = wr + ((size_t)(j * 8 + h)) * 4096;
    const float* wib = wi + ((size_t)(j * 8 + h)) * 4096;
#pragma unroll
    for (int i = 0; i < 16; ++i) {
        const int t = tid + 256 * i;
        wrs[t] = wrb[t];
        wis[t] = wib[t];
    }
    lds_barrier();

    const int bl = tid >> 6;   // 0..3
    const int f  = tid & 63;   // 0..63
    const float2* xrow = &xs[bl * 64];
    float yr = 0.f, yi = 0.f;
#pragma unroll
    for (int e = 0; e < 64; e += 4) {
        const float4 xa = *(const float4*)&xrow[e];
        const float4 xb = *(const float4*)&xrow[e + 2];
        const float2 xv[4] = {make_float2(xa.x, xa.y), make_float2(xa.z, xa.w),
                              make_float2(xb.x, xb.y), make_float2(xb.z, xb.w)};
#pragma unroll
        for (int d = 0; d < 4; ++d) {
            const float a = wrs[(e + d) * 64 + f], cc = wis[(e + d) * 64 + f];
            yr = __builtin_fmaf(xv[d].x, a, yr); yr = __builtin_fmaf(-xv[d].y, cc, yr);
            yi = __builtin_fmaf(xv[d].x, cc, yi); yi = __builtin_fmaf( xv[d].y, a, yi);
        }
    }
    const int b  = bq * 4 + bl;
    const int hf = h * 64 + f;
    _Float16* yt = Yt + ((size_t)b * 512 + (size_t)hf) * 128;
    yt[j]      = (_Float16)(j == 0 ? 0.5f * yr : yr);
    yt[64 + j] = (_Float16)yi;
}

// ---------------- MFMA synthesis: out[b, l, hf] = (2/N) * sum_k Af[l,k] * Yt[b,hf,k] ----------
// grid: 4096 blocks = (b:16, ng:4, lt:64). Block: 64 l x 128 hf, K=128. 4 waves, each 64x32.
__global__ __launch_bounds__(256) void k_synth(const _Float16* __restrict__ Af,
                                               const _Float16* __restrict__ Yt,
                                               float* __restrict__ out) {
    const int tid  = threadIdx.x;
    const int wv   = tid >> 6;
    const int lane = tid & 63;
    const int bi   = blockIdx.x;
    const int b    = bi >> 8;         // 16
    const int ng   = (bi >> 6) & 3;   // 4
    const int lt   = bi & 63;         // 64

    const int l0 = lt * 64;
    const int n0 = ng * 128 + wv * 32;

    const int row = lane & 15;        // A-row / B-col / C-col
    const int kb  = lane >> 4;        // k-block 0..3

    f32x4 acc[4][2] = {};

    const _Float16* Ab = Af + (size_t)l0 * 128;
    const _Float16* Bb = Yt + (size_t)b * 512 * 128 + (size_t)n0 * 128;

#pragma unroll
    for (int k0 = 0; k0 < 128; k0 += 32) {
        f16x8 a[4], bf[2];
#pragma unroll
        for (int mt = 0; mt < 4; ++mt)
            a[mt] = *(const f16x8*)(Ab + (size_t)(mt * 16 + row) * 128 + k0 + kb * 8);
#pragma unroll
        for (int nt = 0; nt < 2; ++nt)
            bf[nt] = *(const f16x8*)(Bb + (size_t)(nt * 16 + row) * 128 + k0 + kb * 8);
#pragma unroll
        for (int mt = 0; mt < 4; ++mt)
#pragma unroll
            for (int nt = 0; nt < 2; ++nt)
                acc[mt][nt] = __builtin_amdgcn_mfma_f32_16x16x32_f16(a[mt], bf[nt],
                                                                     acc[mt][nt], 0, 0, 0);
    }

    const float s = 2.0f / 4096.0f;
#pragma unroll
    for (int mt = 0; mt < 4; ++mt) {
#pragma unroll
        for (int nt = 0; nt < 2; ++nt) {
            const int col = n0 + nt * 16 + row;  // hf
#pragma unroll
            for (int r = 0; r < 4; ++r) {
                const int mrow = mt * 16 + kb * 4 + r;
                out[((size_t)(b * 4096 + l0 + mrow)) * 512 + col] = acc[mt][nt][r] * s;
            }
        }
    }
}

// ---------------- launch ----------------
extern "C" void kernel_launch(void* const* d_in, const int* in_sizes, int n_in,
                              void* d_out, int out_size, void* d_ws, size_t ws_size,
                              hipStream_t stream) {
    const float* q  = (const float*)d_in[0];
    const float* wr = (const float*)d_in[3];
    const float* wi = (const float*)d_in[4];

    char* ws = (char*)d_ws;
    float2*             trig  = (float2*)(ws + 0);                  // 32 KB
    unsigned long long* score = (unsigned long long*)(ws + 32768);  // 16 KB
    int*                idx   = (int*)(ws + 49152);                 // 256 B
    _Float16*           Af    = (_Float16*)(ws + 65536);            // 1 MB
    _Float16*           Yt    = (_Float16*)(ws + 65536 + 1048576);  // 2 MB

    // d_out triples as: transposed-q scratch T -> fp16 spectrum (in-place, per-octet regions)
    // -> final output.
    float2* Xs = (float2*)d_out;

    k_init<<<2064, 256, 0, stream>>>(trig, score, Af);   // trig + score + Af in one dispatch
    k_xpose<<<4096, 256, 0, stream>>>(q, Xs);            // (b:16, h:8, c5:32), 128-row tiles
    k_fft<<<1024, 256, 0, stream>>>(trig, Xs, score);    // radix-16 x3, fp16 spectrum store
    k_topk<<<8, 256, 0, stream>>>(score, idx);           // 2048 candidates, 1/thread
    k_proj<<<2048, 256, 0, stream>>>((const __half2*)Xs, wr, wi, idx, Yt);  // -> fp16 Bt
    k_synth<<<4096, 256, 0, stream>>>(Af, Yt, (float*)d_out);               // MFMA GEMM
}